// Round 1
// baseline (1974.304 us; speedup 1.0000x reference)
//
#include <hip/hip_runtime.h>
#include <math.h>

#define HH 256
#define WW 256
#define NB 4
#define NC 128
#define C4 32

__device__ __forceinline__ float gelu_f(float v) {
    return 0.5f * v * (1.0f + erff(v * 0.7071067811865476f));
}

// ---------------------------------------------------------------- att_xy ----
__global__ void attxy_kernel(const float* __restrict__ params,
                             const float* __restrict__ dww, const float* __restrict__ dwb,
                             const float* __restrict__ pww, const float* __restrict__ pwb,
                             float* __restrict__ att)
{
    __shared__ float P[2048];
    __shared__ float DW[288];
    __shared__ float PW[1024];
    for (int i = threadIdx.x; i < 2048; i += 256) P[i] = params[i];
    for (int i = threadIdx.x; i < 288;  i += 256) DW[i] = dww[i];
    for (int i = threadIdx.x; i < 1024; i += 256) PW[i] = pww[i];
    __syncthreads();
    const int idx = blockIdx.x * 256 + threadIdx.x;
    const int h = idx >> 8, w = idx & 255;

    int iy0[3], iy1[3], ix0[3], ix1[3];
    float fy[3], fx[3];
    bool vy[3], vx[3];
#pragma unroll
    for (int d = 0; d < 3; ++d) {
        int hh = h - 1 + d;
        vy[d] = (hh >= 0 && hh < HH);
        float cy = hh * (7.0f / 255.0f);
        int i0 = (int)floorf(cy); i0 = min(max(i0, 0), 7);
        iy0[d] = i0; iy1[d] = min(i0 + 1, 7); fy[d] = cy - (float)i0;
        int ww2 = w - 1 + d;
        vx[d] = (ww2 >= 0 && ww2 < WW);
        float cx = ww2 * (7.0f / 255.0f);
        int j0 = (int)floorf(cx); j0 = min(max(j0, 0), 7);
        ix0[d] = j0; ix1[d] = min(j0 + 1, 7); fx[d] = cx - (float)j0;
    }
    float g[32];
#pragma unroll
    for (int c = 0; c < 32; ++c) {
        float a = dwb[c];
        const float* Pc = P + c * 64;
#pragma unroll
        for (int dy = 0; dy < 3; ++dy) {
            if (!vy[dy]) continue;
#pragma unroll
            for (int dx = 0; dx < 3; ++dx) {
                if (!vx[dx]) continue;
                float p00 = Pc[iy0[dy] * 8 + ix0[dx]];
                float p01 = Pc[iy0[dy] * 8 + ix1[dx]];
                float p10 = Pc[iy1[dy] * 8 + ix0[dx]];
                float p11 = Pc[iy1[dy] * 8 + ix1[dx]];
                float pt = p00 + (p01 - p00) * fx[dx];
                float pb = p10 + (p11 - p10) * fx[dx];
                float p  = pt + (pb - pt) * fy[dy];
                a += DW[c * 9 + dy * 3 + dx] * p;
            }
        }
        g[c] = gelu_f(a);
    }
#pragma unroll
    for (int co = 0; co < 32; ++co) {
        float a = pwb[co];
#pragma unroll
        for (int c = 0; c < 32; ++c) a += PW[co * 32 + c] * g[c];
        att[co * 65536 + idx] = a;
    }
}

// ------------------------------------------------------------ att_zx/zy ----
__global__ void attz_kernel(const float* __restrict__ params_zx, const float* __restrict__ zx_dww,
                            const float* __restrict__ zx_dwb, const float* __restrict__ zx_pww,
                            const float* __restrict__ zx_pwb,
                            const float* __restrict__ params_zy, const float* __restrict__ zy_dww,
                            const float* __restrict__ zy_dwb, const float* __restrict__ zy_pww,
                            const float* __restrict__ zy_pwb,
                            float* __restrict__ att_zx, float* __restrict__ att_zy)
{
    const bool sel = (blockIdx.x != 0);
    const float* params = sel ? params_zy : params_zx;
    const float* dww = sel ? zy_dww : zx_dww;
    const float* dwb = sel ? zy_dwb : zx_dwb;
    const float* pww = sel ? zy_pww : zx_pww;
    const float* pwb = sel ? zy_pwb : zx_pwb;
    float* att = sel ? att_zy : att_zx;
    const int pos = threadIdx.x;
    float g[32];
#pragma unroll
    for (int c = 0; c < 32; ++c) {
        float a = dwb[c];
#pragma unroll
        for (int d = 0; d < 3; ++d) {
            int p = pos - 1 + d;
            if (p < 0 || p > 255) continue;
            float cz = p * (7.0f / 255.0f);
            int i0 = (int)floorf(cz); i0 = min(max(i0, 0), 7);
            int i1 = min(i0 + 1, 7);
            float f = cz - (float)i0;
            float pv = params[c * 8 + i0];
            pv += (params[c * 8 + i1] - pv) * f;
            a += dww[c * 3 + d] * pv;
        }
        g[c] = gelu_f(a);
    }
#pragma unroll
    for (int co = 0; co < 32; ++co) {
        float a = pwb[co];
#pragma unroll
        for (int ci = 0; ci < 32; ++ci) a += pww[co * 32 + ci] * g[ci];
        att[co * 256 + pos] = a;
    }
}

// -------------------------------------------------------- pw transpose ----
__global__ void transpose_pw_kernel(const float* __restrict__ pw, float* __restrict__ pwT) {
    int i = blockIdx.x * 256 + threadIdx.x;   // i = co*128+ci
    int co = i >> 7, ci = i & 127;
    pwT[ci * 128 + co] = pw[i];
}

// ---------------------------------------------------------- fused main ----
// LN1 -> {att multiplies | pw+gelu+dw3x3 on x4} -> LN2 + residual -> z
#define TH_C 4
__global__ __launch_bounds__(1024) void fused_main_kernel(
    const float* __restrict__ x,
    const float* __restrict__ n1w, const float* __restrict__ n1b,
    const float* __restrict__ dw_pw_w, const float* __restrict__ dw_pw_b,
    const float* __restrict__ dw_dw_w, const float* __restrict__ dw_dw_b,
    const float* __restrict__ n2w, const float* __restrict__ n2b,
    const float* __restrict__ att_xy, const float* __restrict__ att_zx,
    const float* __restrict__ att_zy,
    float* __restrict__ zout)
{
    __shared__ float g4[3][32][256];   // 96 KB ring: gelu(pw(x4)) rows h-1,h,h+1
    __shared__ float red_s[4][256];
    __shared__ float red_q[4][256];

    const int b     = blockIdx.x >> 6;
    const int h0    = (blockIdx.x & 63) * TH_C;
    const int chunk = threadIdx.x >> 8;          // 0..3  -> channels [32c,32c+32)
    const int w     = threadIdx.x & 255;
    const int cbase = chunk * 32;

    float xn[2][32];   // LN1 output double buffer (static-indexed via full unroll)
    float tmp[32];     // scratch: x values during load, y values during emit

#pragma unroll
    for (int rr = -1; rr <= TH_C; ++rr) {
        const int h    = h0 + rr;
        const int slot = (rr + 1) % 3;
        const int cur  = (rr + 1) & 1;
        const bool hv  = (h >= 0) && (h < HH);   // block-uniform

        // ---- load row h, LN1 stats ----
        float s1 = 0.f, s2 = 0.f;
        if (hv) {
            const float* xp = x + (((size_t)b * NC + cbase) * HH + h) * WW + w;
#pragma unroll
            for (int k = 0; k < 32; ++k) {
                float v = xp[(size_t)k * 65536];
                tmp[k] = v; s1 += v; s2 += v * v;
            }
        }
        red_s[chunk][w] = s1;
        red_q[chunk][w] = s2;
        __syncthreads();
        {
            float ssum = red_s[0][w] + red_s[1][w] + red_s[2][w] + red_s[3][w];
            float qsum = red_q[0][w] + red_q[1][w] + red_q[2][w] + red_q[3][w];
            float mean = ssum * (1.f / 128.f);
            float var  = qsum * (1.f / 128.f) - mean * mean;
            float rstd = rsqrtf(var + 1e-6f);
            if (hv) {
#pragma unroll
                for (int k = 0; k < 32; ++k) {
                    int c = cbase + k;
                    xn[cur][k] = (tmp[k] - mean) * rstd * n1w[c] + n1b[c];
                }
            }
        }
        // ---- g4 row: gelu(pw(x4)) (chunk 3 only), or zero-pad row ----
        if (hv) {
            if (chunk == 3) {
#pragma unroll
                for (int co = 0; co < 32; ++co) {
                    float a = dw_pw_b[co];
#pragma unroll
                    for (int k = 0; k < 32; ++k) a += dw_pw_w[co * 32 + k] * xn[cur][k];
                    g4[slot][co][w] = gelu_f(a);
                }
            }
        } else {
#pragma unroll
            for (int j = 0; j < 8; ++j) g4[slot][chunk * 8 + j][w] = 0.f;
        }
        __syncthreads();

        // ---- emit row he = h-1 ----
        if (rr >= 1) {
            const int he = h - 1;
            const int pv = rr & 1;
            float e1 = 0.f, e2 = 0.f;
            if (chunk == 0) {
                const float* ap = att_xy + he * WW + w;
#pragma unroll
                for (int k = 0; k < 32; ++k) {
                    float yv = xn[pv][k] * ap[(size_t)k * 65536];
                    tmp[k] = yv; e1 += yv; e2 += yv * yv;
                }
            } else if (chunk == 1) {
#pragma unroll
                for (int k = 0; k < 32; ++k) {
                    float yv = xn[pv][k] * att_zx[k * 256 + he];
                    tmp[k] = yv; e1 += yv; e2 += yv * yv;
                }
            } else if (chunk == 2) {
#pragma unroll
                for (int k = 0; k < 32; ++k) {
                    float yv = xn[pv][k] * att_zy[k * 256 + w];
                    tmp[k] = yv; e1 += yv; e2 += yv * yv;
                }
            } else {
                const int sa = (rr - 1) % 3, sb = rr % 3, sc = (rr + 1) % 3;
#pragma unroll
                for (int k = 0; k < 32; ++k) {
                    float a = dw_dw_b[k];
                    const float* wk = dw_dw_w + k * 9;
                    {
                        const float* gr = &g4[sa][k][0];
                        if (w > 0)   a += wk[0] * gr[w - 1];
                                     a += wk[1] * gr[w];
                        if (w < 255) a += wk[2] * gr[w + 1];
                    }
                    {
                        const float* gr = &g4[sb][k][0];
                        if (w > 0)   a += wk[3] * gr[w - 1];
                                     a += wk[4] * gr[w];
                        if (w < 255) a += wk[5] * gr[w + 1];
                    }
                    {
                        const float* gr = &g4[sc][k][0];
                        if (w > 0)   a += wk[6] * gr[w - 1];
                                     a += wk[7] * gr[w];
                        if (w < 255) a += wk[8] * gr[w + 1];
                    }
                    tmp[k] = a; e1 += a; e2 += a * a;
                }
            }
            red_s[chunk][w] = e1;
            red_q[chunk][w] = e2;
            __syncthreads();
            float ssum = red_s[0][w] + red_s[1][w] + red_s[2][w] + red_s[3][w];
            float qsum = red_q[0][w] + red_q[1][w] + red_q[2][w] + red_q[3][w];
            float mean = ssum * (1.f / 128.f);
            float var  = qsum * (1.f / 128.f) - mean * mean;
            float rstd = rsqrtf(var + 1e-6f);
            float* zp = zout + (((size_t)b * NC + cbase) * HH + he) * WW + w;
#pragma unroll
            for (int k = 0; k < 32; ++k) {
                int c = cbase + k;
                zp[(size_t)k * 65536] = (tmp[k] - mean) * rstd * n2w[c] + n2b[c] + xn[pv][k];
            }
            __syncthreads();
        }
    }
}

// --------------------------------------------------------------- ldw ----
// z -> depthwise 3x3 -> gelu (LDS) -> 1x1 128->128 -> out
#define TD 4
__global__ __launch_bounds__(256) void ldw_kernel(
    const float* __restrict__ z, const float* __restrict__ dww,
    const float* __restrict__ dwb, const float* __restrict__ pwT,
    const float* __restrict__ pwb, float* __restrict__ out)
{
    __shared__ float tl[128][64];   // 32 KB
    const int wt = blockIdx.x & 3;
    const int hs = (blockIdx.x >> 2) & 63;
    const int b  = blockIdx.x >> 8;
    const int chunk = threadIdx.x >> 6;
    const int lane  = threadIdx.x & 63;
    const int w  = wt * 64 + lane;
    const int h0 = hs * TD;
    const int cobase = chunk * 32;

    for (int r = 0; r < TD; ++r) {
        const int h = h0 + r;
        // depthwise 3x3 + gelu for this block's 128 channels x 64 pixels
#pragma unroll
        for (int k = 0; k < 32; ++k) {
            const int c = cobase + k;
            const float* wk = dww + c * 9;
            float a = dwb[c];
            const float* zc = z + ((size_t)(b * NC + c) * HH) * WW;
#pragma unroll
            for (int dy = -1; dy <= 1; ++dy) {
                int hy = h + dy;
                if (hy < 0 || hy > 255) continue;
                const float* zr = zc + (size_t)hy * WW;
                const float* wr = wk + (dy + 1) * 3;
                if (w > 0)   a += wr[0] * zr[w - 1];
                             a += wr[1] * zr[w];
                if (w < 255) a += wr[2] * zr[w + 1];
            }
            tl[c][lane] = gelu_f(a);
        }
        __syncthreads();
        // 1x1 conv: 128 -> 128, scalar weights from transposed matrix
        float acc[32];
#pragma unroll
        for (int k = 0; k < 32; ++k) acc[k] = pwb[cobase + k];
        const int cob = __builtin_amdgcn_readfirstlane(cobase);
        for (int ci = 0; ci < 128; ++ci) {
            float tv = tl[ci][lane];
            const float4* wp = (const float4*)(pwT + ci * 128 + cob);
#pragma unroll
            for (int q = 0; q < 8; ++q) {
                float4 wv = wp[q];
                acc[q * 4 + 0] += wv.x * tv;
                acc[q * 4 + 1] += wv.y * tv;
                acc[q * 4 + 2] += wv.z * tv;
                acc[q * 4 + 3] += wv.w * tv;
            }
        }
        float* op = out + (((size_t)b * NC + cobase) * HH + h) * WW + w;
#pragma unroll
        for (int k = 0; k < 32; ++k) op[(size_t)k * 65536] = acc[k];
        __syncthreads();
    }
}

// ------------------------------------------------------------- launch ----
extern "C" void kernel_launch(void* const* d_in, const int* in_sizes, int n_in,
                              void* d_out, int out_size, void* d_ws, size_t ws_size,
                              hipStream_t stream)
{
    (void)in_sizes; (void)n_in; (void)out_size; (void)ws_size;
    const float* x       = (const float*)d_in[0];
    const float* n1w     = (const float*)d_in[1];
    const float* n1b     = (const float*)d_in[2];
    const float* pxy     = (const float*)d_in[3];
    const float* cxy_dww = (const float*)d_in[4];
    const float* cxy_dwb = (const float*)d_in[5];
    const float* cxy_pww = (const float*)d_in[6];
    const float* cxy_pwb = (const float*)d_in[7];
    const float* pzx     = (const float*)d_in[8];
    const float* czx_dww = (const float*)d_in[9];
    const float* czx_dwb = (const float*)d_in[10];
    const float* czx_pww = (const float*)d_in[11];
    const float* czx_pwb = (const float*)d_in[12];
    const float* pzy     = (const float*)d_in[13];
    const float* czy_dww = (const float*)d_in[14];
    const float* czy_dwb = (const float*)d_in[15];
    const float* czy_pww = (const float*)d_in[16];
    const float* czy_pwb = (const float*)d_in[17];
    const float* dw_pww  = (const float*)d_in[18];
    const float* dw_pwb  = (const float*)d_in[19];
    const float* dw_dww  = (const float*)d_in[20];
    const float* dw_dwb  = (const float*)d_in[21];
    const float* n2w     = (const float*)d_in[22];
    const float* n2b     = (const float*)d_in[23];
    const float* ldw_dww = (const float*)d_in[24];
    const float* ldw_dwb = (const float*)d_in[25];
    const float* ldw_pww = (const float*)d_in[26];
    const float* ldw_pwb = (const float*)d_in[27];
    float* out = (float*)d_out;
    float* ws  = (float*)d_ws;

    float* att_xy = ws;                       // 32*65536
    float* att_zx = att_xy + 32 * 65536;      // 32*256
    float* att_zy = att_zx + 32 * 256;        // 32*256
    float* pwT    = att_zy + 32 * 256;        // 128*128
    float* zbuf   = pwT + 128 * 128;          // 4*128*256*256

    attxy_kernel<<<256, 256, 0, stream>>>(pxy, cxy_dww, cxy_dwb, cxy_pww, cxy_pwb, att_xy);
    attz_kernel<<<2, 256, 0, stream>>>(pzx, czx_dww, czx_dwb, czx_pww, czx_pwb,
                                       pzy, czy_dww, czy_dwb, czy_pww, czy_pwb,
                                       att_zx, att_zy);
    transpose_pw_kernel<<<64, 256, 0, stream>>>(ldw_pww, pwT);
    fused_main_kernel<<<256, 1024, 0, stream>>>(x, n1w, n1b, dw_pww, dw_pwb, dw_dww, dw_dwb,
                                                n2w, n2b, att_xy, att_zx, att_zy, zbuf);
    ldw_kernel<<<1024, 256, 0, stream>>>(zbuf, ldw_dww, ldw_dwb, pwT, ldw_pwb, out);
}

// Round 2
// 992.234 us; speedup vs baseline: 1.9898x; 1.9898x over previous
//
#include <hip/hip_runtime.h>
#include <hip/hip_bf16.h>
#include <math.h>

#define HH 256
#define WW 256
#define NB 4
#define NC 128
#define C4 32

__device__ __forceinline__ float gelu_f(float v) {
    return 0.5f * v * (1.0f + erff(v * 0.7071067811865476f));
}
__device__ __forceinline__ float bflo(unsigned u) { return __uint_as_float(u << 16); }
__device__ __forceinline__ float bfhi(unsigned u) { return __uint_as_float(u & 0xffff0000u); }

// ---------------------------------------------------------------- att_xy ----
__global__ void attxy_kernel(const float* __restrict__ params,
                             const float* __restrict__ dww, const float* __restrict__ dwb,
                             const float* __restrict__ pww, const float* __restrict__ pwb,
                             float* __restrict__ att)
{
    __shared__ float P[2048];
    __shared__ float DW[288];
    __shared__ float PW[1024];
    for (int i = threadIdx.x; i < 2048; i += 256) P[i] = params[i];
    for (int i = threadIdx.x; i < 288;  i += 256) DW[i] = dww[i];
    for (int i = threadIdx.x; i < 1024; i += 256) PW[i] = pww[i];
    __syncthreads();
    const int idx = blockIdx.x * 256 + threadIdx.x;
    const int h = idx >> 8, w = idx & 255;

    int iy0[3], iy1[3], ix0[3], ix1[3];
    float fy[3], fx[3];
    bool vy[3], vx[3];
#pragma unroll
    for (int d = 0; d < 3; ++d) {
        int hh = h - 1 + d;
        vy[d] = (hh >= 0 && hh < HH);
        float cy = hh * (7.0f / 255.0f);
        int i0 = (int)floorf(cy); i0 = min(max(i0, 0), 7);
        iy0[d] = i0; iy1[d] = min(i0 + 1, 7); fy[d] = cy - (float)i0;
        int ww2 = w - 1 + d;
        vx[d] = (ww2 >= 0 && ww2 < WW);
        float cx = ww2 * (7.0f / 255.0f);
        int j0 = (int)floorf(cx); j0 = min(max(j0, 0), 7);
        ix0[d] = j0; ix1[d] = min(j0 + 1, 7); fx[d] = cx - (float)j0;
    }
    float g[32];
#pragma unroll
    for (int c = 0; c < 32; ++c) {
        float a = dwb[c];
        const float* Pc = P + c * 64;
#pragma unroll
        for (int dy = 0; dy < 3; ++dy) {
            if (!vy[dy]) continue;
#pragma unroll
            for (int dx = 0; dx < 3; ++dx) {
                if (!vx[dx]) continue;
                float p00 = Pc[iy0[dy] * 8 + ix0[dx]];
                float p01 = Pc[iy0[dy] * 8 + ix1[dx]];
                float p10 = Pc[iy1[dy] * 8 + ix0[dx]];
                float p11 = Pc[iy1[dy] * 8 + ix1[dx]];
                float pt = p00 + (p01 - p00) * fx[dx];
                float pb = p10 + (p11 - p10) * fx[dx];
                float p  = pt + (pb - pt) * fy[dy];
                a += DW[c * 9 + dy * 3 + dx] * p;
            }
        }
        g[c] = gelu_f(a);
    }
#pragma unroll
    for (int co = 0; co < 32; ++co) {
        float a = pwb[co];
#pragma unroll
        for (int c = 0; c < 32; ++c) a += PW[co * 32 + c] * g[c];
        att[co * 65536 + idx] = a;
    }
}

// ------------------------------------------------------------ att_zx/zy ----
__global__ void attz_kernel(const float* __restrict__ params_zx, const float* __restrict__ zx_dww,
                            const float* __restrict__ zx_dwb, const float* __restrict__ zx_pww,
                            const float* __restrict__ zx_pwb,
                            const float* __restrict__ params_zy, const float* __restrict__ zy_dww,
                            const float* __restrict__ zy_dwb, const float* __restrict__ zy_pww,
                            const float* __restrict__ zy_pwb,
                            float* __restrict__ att_zx, float* __restrict__ att_zy)
{
    const bool sel = (blockIdx.x != 0);
    const float* params = sel ? params_zy : params_zx;
    const float* dww = sel ? zy_dww : zx_dww;
    const float* dwb = sel ? zy_dwb : zx_dwb;
    const float* pww = sel ? zy_pww : zx_pww;
    const float* pwb = sel ? zy_pwb : zx_pwb;
    float* att = sel ? att_zy : att_zx;
    const int pos = threadIdx.x;
    float g[32];
#pragma unroll
    for (int c = 0; c < 32; ++c) {
        float a = dwb[c];
#pragma unroll
        for (int d = 0; d < 3; ++d) {
            int p = pos - 1 + d;
            if (p < 0 || p > 255) continue;
            float cz = p * (7.0f / 255.0f);
            int i0 = (int)floorf(cz); i0 = min(max(i0, 0), 7);
            int i1 = min(i0 + 1, 7);
            float f = cz - (float)i0;
            float pv = params[c * 8 + i0];
            pv += (params[c * 8 + i1] - pv) * f;
            a += dww[c * 3 + d] * pv;
        }
        g[c] = gelu_f(a);
    }
#pragma unroll
    for (int co = 0; co < 32; ++co) {
        float a = pwb[co];
#pragma unroll
        for (int ci = 0; ci < 32; ++ci) a += pww[co * 32 + ci] * g[ci];
        att[co * 256 + pos] = a;
    }
}

// ------------------------------------------- pw transpose -> bf16 [ci][co] --
__global__ void transpose_pw_kernel(const float* __restrict__ pw, __hip_bfloat16* __restrict__ pwTb) {
    int i = blockIdx.x * 256 + threadIdx.x;   // i = co*128+ci
    int co = i >> 7, ci = i & 127;
    pwTb[ci * 128 + co] = __float2bfloat16(pw[i]);
}

// ---------------------------------------------------------- fused main ----
// LN1 -> {att multiplies | pw+gelu+dw3x3 on x4} -> LN2 + residual -> z
#define TH_C 4
__global__ __launch_bounds__(1024) void fused_main_kernel(
    const float* __restrict__ x,
    const float* __restrict__ n1w, const float* __restrict__ n1b,
    const float* __restrict__ dw_pw_w, const float* __restrict__ dw_pw_b,
    const float* __restrict__ dw_dw_w, const float* __restrict__ dw_dw_b,
    const float* __restrict__ n2w, const float* __restrict__ n2b,
    const float* __restrict__ att_xy, const float* __restrict__ att_zx,
    const float* __restrict__ att_zy,
    float* __restrict__ zout)
{
    __shared__ float g4[3][32][256];   // 96 KB ring: gelu(pw(x4)) rows h-1,h,h+1
    __shared__ float red_s[4][256];
    __shared__ float red_q[4][256];

    const int b     = blockIdx.x >> 6;
    const int h0    = (blockIdx.x & 63) * TH_C;
    const int chunk = threadIdx.x >> 8;          // 0..3  -> channels [32c,32c+32)
    const int w     = threadIdx.x & 255;
    const int cbase = chunk * 32;

    float xn[2][32];   // LN1 output double buffer (static-indexed via full unroll)
    float tmp[32];     // scratch: x values during load, y values during emit

#pragma unroll
    for (int rr = -1; rr <= TH_C; ++rr) {
        const int h    = h0 + rr;
        const int slot = (rr + 1) % 3;
        const int cur  = (rr + 1) & 1;
        const bool hv  = (h >= 0) && (h < HH);   // block-uniform

        // ---- load row h, LN1 stats ----
        float s1 = 0.f, s2 = 0.f;
        if (hv) {
            const float* xp = x + (((size_t)b * NC + cbase) * HH + h) * WW + w;
#pragma unroll
            for (int k = 0; k < 32; ++k) {
                float v = xp[(size_t)k * 65536];
                tmp[k] = v; s1 += v; s2 += v * v;
            }
        }
        red_s[chunk][w] = s1;
        red_q[chunk][w] = s2;
        __syncthreads();
        {
            float ssum = red_s[0][w] + red_s[1][w] + red_s[2][w] + red_s[3][w];
            float qsum = red_q[0][w] + red_q[1][w] + red_q[2][w] + red_q[3][w];
            float mean = ssum * (1.f / 128.f);
            float var  = qsum * (1.f / 128.f) - mean * mean;
            float rstd = rsqrtf(var + 1e-6f);
            if (hv) {
#pragma unroll
                for (int k = 0; k < 32; ++k) {
                    int c = cbase + k;
                    xn[cur][k] = (tmp[k] - mean) * rstd * n1w[c] + n1b[c];
                }
            }
        }
        // ---- g4 row: gelu(pw(x4)) (chunk 3 only), or zero-pad row ----
        if (hv) {
            if (chunk == 3) {
#pragma unroll
                for (int co = 0; co < 32; ++co) {
                    float a = dw_pw_b[co];
#pragma unroll
                    for (int k = 0; k < 32; ++k) a += dw_pw_w[co * 32 + k] * xn[cur][k];
                    g4[slot][co][w] = gelu_f(a);
                }
            }
        } else {
#pragma unroll
            for (int j = 0; j < 8; ++j) g4[slot][chunk * 8 + j][w] = 0.f;
        }
        __syncthreads();

        // ---- emit row he = h-1 ----
        if (rr >= 1) {
            const int he = h - 1;
            const int pv = rr & 1;
            float e1 = 0.f, e2 = 0.f;
            if (chunk == 0) {
                const float* ap = att_xy + he * WW + w;
#pragma unroll
                for (int k = 0; k < 32; ++k) {
                    float yv = xn[pv][k] * ap[(size_t)k * 65536];
                    tmp[k] = yv; e1 += yv; e2 += yv * yv;
                }
            } else if (chunk == 1) {
#pragma unroll
                for (int k = 0; k < 32; ++k) {
                    float yv = xn[pv][k] * att_zx[k * 256 + he];
                    tmp[k] = yv; e1 += yv; e2 += yv * yv;
                }
            } else if (chunk == 2) {
#pragma unroll
                for (int k = 0; k < 32; ++k) {
                    float yv = xn[pv][k] * att_zy[k * 256 + w];
                    tmp[k] = yv; e1 += yv; e2 += yv * yv;
                }
            } else {
                const int sa = (rr - 1) % 3, sb = rr % 3, sc = (rr + 1) % 3;
#pragma unroll
                for (int k = 0; k < 32; ++k) {
                    float a = dw_dw_b[k];
                    const float* wk = dw_dw_w + k * 9;
                    {
                        const float* gr = &g4[sa][k][0];
                        if (w > 0)   a += wk[0] * gr[w - 1];
                                     a += wk[1] * gr[w];
                        if (w < 255) a += wk[2] * gr[w + 1];
                    }
                    {
                        const float* gr = &g4[sb][k][0];
                        if (w > 0)   a += wk[3] * gr[w - 1];
                                     a += wk[4] * gr[w];
                        if (w < 255) a += wk[5] * gr[w + 1];
                    }
                    {
                        const float* gr = &g4[sc][k][0];
                        if (w > 0)   a += wk[6] * gr[w - 1];
                                     a += wk[7] * gr[w];
                        if (w < 255) a += wk[8] * gr[w + 1];
                    }
                    tmp[k] = a; e1 += a; e2 += a * a;
                }
            }
            red_s[chunk][w] = e1;
            red_q[chunk][w] = e2;
            __syncthreads();
            float ssum = red_s[0][w] + red_s[1][w] + red_s[2][w] + red_s[3][w];
            float qsum = red_q[0][w] + red_q[1][w] + red_q[2][w] + red_q[3][w];
            float mean = ssum * (1.f / 128.f);
            float var  = qsum * (1.f / 128.f) - mean * mean;
            float rstd = rsqrtf(var + 1e-6f);
            float* zp = zout + (((size_t)b * NC + cbase) * HH + he) * WW + w;
#pragma unroll
            for (int k = 0; k < 32; ++k) {
                int c = cbase + k;
                zp[(size_t)k * 65536] = (tmp[k] - mean) * rstd * n2w[c] + n2b[c] + xn[pv][k];
            }
            __syncthreads();
        }
    }
}

// --------------------------------------------------------------- ldw ----
// z -> depthwise 3x3 -> gelu (LDS) -> 1x1 128->128 (register-tiled, bf16 W) -> out
// Per block: one (b, h, 64-px) tile. 256 threads.
//   Phase 1: tl[128][64] = gelu(dw3x3(z))          (32 KB LDS)
//   Phase 2: wl[128][128] bf16 weights [ci][co]    (32 KB LDS)
//            each thread: 4 co x 8 px accumulators, loop ci=0..127
__global__ __launch_bounds__(256) void ldw_kernel(
    const float* __restrict__ z, const float* __restrict__ dww,
    const float* __restrict__ dwb, const __hip_bfloat16* __restrict__ wT,
    const float* __restrict__ pwb, float* __restrict__ out)
{
    __shared__ float tl[128][64];                 // 32 KB
    __shared__ __hip_bfloat16 wl[128][128];       // 32 KB

    // stage bf16 weights (uint4 = 8 bf16 each; 2048 uint4 total)
    {
        const uint4* src = (const uint4*)wT;
        uint4* dst = (uint4*)&wl[0][0];
#pragma unroll
        for (int i = 0; i < 8; ++i) dst[threadIdx.x + i * 256] = src[threadIdx.x + i * 256];
    }

    const int b    = blockIdx.x >> 10;            // 4 * 256 * 4 = 4096 blocks
    const int h    = (blockIdx.x >> 2) & 255;
    const int px0  = (blockIdx.x & 3) * 64;
    const int lane = threadIdx.x & 63;
    const int cg   = threadIdx.x >> 6;            // 0..3 -> 32 channels each
    const int w    = px0 + lane;

    // ---- phase 1: depthwise 3x3 + gelu ----
#pragma unroll
    for (int k = 0; k < 32; ++k) {
        const int c = cg * 32 + k;
        const float* wk = dww + c * 9;
        float a = dwb[c];
        const float* zc = z + ((size_t)(b * NC + c) * HH) * WW;
#pragma unroll
        for (int dy = -1; dy <= 1; ++dy) {
            int hy = h + dy;
            if (hy < 0 || hy > 255) continue;
            const float* zr = zc + (size_t)hy * WW;
            const float* wr = wk + (dy + 1) * 3;
            if (w > 0)   a += wr[0] * zr[w - 1];
                         a += wr[1] * zr[w];
            if (w < 255) a += wr[2] * zr[w + 1];
        }
        tl[c][lane] = gelu_f(a);
    }
    __syncthreads();

    // ---- phase 2: 1x1 conv 128 -> 128 ----
    const int co0 = (threadIdx.x >> 3) * 4;       // 32 co-groups of 4
    const int pl0 = (threadIdx.x & 7) * 8;        // 8 px-groups of 8
    float acc[4][8];
#pragma unroll
    for (int j = 0; j < 4; ++j) {
        float bv = pwb[co0 + j];
#pragma unroll
        for (int i = 0; i < 8; ++i) acc[j][i] = bv;
    }
#pragma unroll 2
    for (int ci = 0; ci < 128; ++ci) {
        float4 t0 = *(const float4*)&tl[ci][pl0];
        float4 t1 = *(const float4*)&tl[ci][pl0 + 4];
        uint2 wp = *(const uint2*)&wl[ci][co0];
        float w0 = bflo(wp.x), w1 = bfhi(wp.x);
        float w2 = bflo(wp.y), w3 = bfhi(wp.y);
        float tv[8] = {t0.x, t0.y, t0.z, t0.w, t1.x, t1.y, t1.z, t1.w};
        float wv[4] = {w0, w1, w2, w3};
#pragma unroll
        for (int j = 0; j < 4; ++j)
#pragma unroll
            for (int i = 0; i < 8; ++i)
                acc[j][i] += wv[j] * tv[i];
    }
    // ---- store: 4 co rows x 8 px ----
#pragma unroll
    for (int j = 0; j < 4; ++j) {
        float* op = out + (((size_t)b * NC + co0 + j) * HH + h) * WW + px0 + pl0;
        float4 s0 = {acc[j][0], acc[j][1], acc[j][2], acc[j][3]};
        float4 s1 = {acc[j][4], acc[j][5], acc[j][6], acc[j][7]};
        *(float4*)op = s0;
        *(float4*)(op + 4) = s1;
    }
}

// ------------------------------------------------------------- launch ----
extern "C" void kernel_launch(void* const* d_in, const int* in_sizes, int n_in,
                              void* d_out, int out_size, void* d_ws, size_t ws_size,
                              hipStream_t stream)
{
    (void)in_sizes; (void)n_in; (void)out_size; (void)ws_size;
    const float* x       = (const float*)d_in[0];
    const float* n1w     = (const float*)d_in[1];
    const float* n1b     = (const float*)d_in[2];
    const float* pxy     = (const float*)d_in[3];
    const float* cxy_dww = (const float*)d_in[4];
    const float* cxy_dwb = (const float*)d_in[5];
    const float* cxy_pww = (const float*)d_in[6];
    const float* cxy_pwb = (const float*)d_in[7];
    const float* pzx     = (const float*)d_in[8];
    const float* czx_dww = (const float*)d_in[9];
    const float* czx_dwb = (const float*)d_in[10];
    const float* czx_pww = (const float*)d_in[11];
    const float* czx_pwb = (const float*)d_in[12];
    const float* pzy     = (const float*)d_in[13];
    const float* czy_dww = (const float*)d_in[14];
    const float* czy_dwb = (const float*)d_in[15];
    const float* czy_pww = (const float*)d_in[16];
    const float* czy_pwb = (const float*)d_in[17];
    const float* dw_pww  = (const float*)d_in[18];
    const float* dw_pwb  = (const float*)d_in[19];
    const float* dw_dww  = (const float*)d_in[20];
    const float* dw_dwb  = (const float*)d_in[21];
    const float* n2w     = (const float*)d_in[22];
    const float* n2b     = (const float*)d_in[23];
    const float* ldw_dww = (const float*)d_in[24];
    const float* ldw_dwb = (const float*)d_in[25];
    const float* ldw_pww = (const float*)d_in[26];
    const float* ldw_pwb = (const float*)d_in[27];
    float* out = (float*)d_out;
    char* ws   = (char*)d_ws;

    float* att_xy = (float*)ws;                                   // 8 MiB
    float* att_zx = att_xy + 32 * 65536;
    float* att_zy = att_zx + 32 * 256;
    __hip_bfloat16* pwTb = (__hip_bfloat16*)(att_zy + 32 * 256);  // 32 KB
    float* zbuf   = (float*)(ws + ((32 * 65536 + 2 * 32 * 256) * 4 + 128 * 128 * 2 + 255) / 256 * 256);

    attxy_kernel<<<256, 256, 0, stream>>>(pxy, cxy_dww, cxy_dwb, cxy_pww, cxy_pwb, att_xy);
    attz_kernel<<<2, 256, 0, stream>>>(pzx, czx_dww, czx_dwb, czx_pww, czx_pwb,
                                       pzy, czy_dww, czy_dwb, czy_pww, czy_pwb,
                                       att_zx, att_zy);
    transpose_pw_kernel<<<64, 256, 0, stream>>>(ldw_pww, pwTb);
    fused_main_kernel<<<256, 1024, 0, stream>>>(x, n1w, n1b, dw_pww, dw_pwb, dw_dww, dw_dwb,
                                                n2w, n2b, att_xy, att_zx, att_zy, zbuf);
    ldw_kernel<<<4096, 256, 0, stream>>>(zbuf, ldw_dww, ldw_dwb, pwTb, ldw_pwb, out);
}

// Round 3
// 952.993 us; speedup vs baseline: 2.0717x; 1.0412x over previous
//
#include <hip/hip_runtime.h>
#include <hip/hip_bf16.h>
#include <math.h>

#define HH 256
#define WW 256
#define NB 4
#define NC 128
#define C4 32

typedef __attribute__((ext_vector_type(8))) short short8v;
typedef __attribute__((ext_vector_type(4))) float float4v;

__device__ __forceinline__ float gelu_f(float v) {
    return 0.5f * v * (1.0f + erff(v * 0.7071067811865476f));
}
__device__ __forceinline__ unsigned short f2bf(float x) {
    __hip_bfloat16 h = __float2bfloat16(x);
    return __builtin_bit_cast(unsigned short, h);
}
__device__ __forceinline__ float bf2f(unsigned short u) {
    return __uint_as_float(((unsigned)u) << 16);
}

// ---------------------------------------------------------------- att_xy ----
__global__ void attxy_kernel(const float* __restrict__ params,
                             const float* __restrict__ dww, const float* __restrict__ dwb,
                             const float* __restrict__ pww, const float* __restrict__ pwb,
                             float* __restrict__ att)
{
    __shared__ float P[2048];
    __shared__ float DW[288];
    __shared__ float PW[1024];
    for (int i = threadIdx.x; i < 2048; i += 256) P[i] = params[i];
    for (int i = threadIdx.x; i < 288;  i += 256) DW[i] = dww[i];
    for (int i = threadIdx.x; i < 1024; i += 256) PW[i] = pww[i];
    __syncthreads();
    const int idx = blockIdx.x * 256 + threadIdx.x;
    const int h = idx >> 8, w = idx & 255;

    int iy0[3], iy1[3], ix0[3], ix1[3];
    float fy[3], fx[3];
    bool vy[3], vx[3];
#pragma unroll
    for (int d = 0; d < 3; ++d) {
        int hh = h - 1 + d;
        vy[d] = (hh >= 0 && hh < HH);
        float cy = hh * (7.0f / 255.0f);
        int i0 = (int)floorf(cy); i0 = min(max(i0, 0), 7);
        iy0[d] = i0; iy1[d] = min(i0 + 1, 7); fy[d] = cy - (float)i0;
        int ww2 = w - 1 + d;
        vx[d] = (ww2 >= 0 && ww2 < WW);
        float cx = ww2 * (7.0f / 255.0f);
        int j0 = (int)floorf(cx); j0 = min(max(j0, 0), 7);
        ix0[d] = j0; ix1[d] = min(j0 + 1, 7); fx[d] = cx - (float)j0;
    }
    float g[32];
#pragma unroll
    for (int c = 0; c < 32; ++c) {
        float a = dwb[c];
        const float* Pc = P + c * 64;
#pragma unroll
        for (int dy = 0; dy < 3; ++dy) {
            if (!vy[dy]) continue;
#pragma unroll
            for (int dx = 0; dx < 3; ++dx) {
                if (!vx[dx]) continue;
                float p00 = Pc[iy0[dy] * 8 + ix0[dx]];
                float p01 = Pc[iy0[dy] * 8 + ix1[dx]];
                float p10 = Pc[iy1[dy] * 8 + ix0[dx]];
                float p11 = Pc[iy1[dy] * 8 + ix1[dx]];
                float pt = p00 + (p01 - p00) * fx[dx];
                float pb = p10 + (p11 - p10) * fx[dx];
                float p  = pt + (pb - pt) * fy[dy];
                a += DW[c * 9 + dy * 3 + dx] * p;
            }
        }
        g[c] = gelu_f(a);
    }
#pragma unroll
    for (int co = 0; co < 32; ++co) {
        float a = pwb[co];
#pragma unroll
        for (int c = 0; c < 32; ++c) a += PW[co * 32 + c] * g[c];
        att[co * 65536 + idx] = a;
    }
}

// ------------------------------------------------------------ att_zx/zy ----
__global__ void attz_kernel(const float* __restrict__ params_zx, const float* __restrict__ zx_dww,
                            const float* __restrict__ zx_dwb, const float* __restrict__ zx_pww,
                            const float* __restrict__ zx_pwb,
                            const float* __restrict__ params_zy, const float* __restrict__ zy_dww,
                            const float* __restrict__ zy_dwb, const float* __restrict__ zy_pww,
                            const float* __restrict__ zy_pwb,
                            float* __restrict__ att_zx, float* __restrict__ att_zy)
{
    const bool sel = (blockIdx.x != 0);
    const float* params = sel ? params_zy : params_zx;
    const float* dww = sel ? zy_dww : zx_dww;
    const float* dwb = sel ? zy_dwb : zx_dwb;
    const float* pww = sel ? zy_pww : zx_pww;
    const float* pwb = sel ? zy_pwb : zx_pwb;
    float* att = sel ? att_zy : att_zx;
    const int pos = threadIdx.x;
    float g[32];
#pragma unroll
    for (int c = 0; c < 32; ++c) {
        float a = dwb[c];
#pragma unroll
        for (int d = 0; d < 3; ++d) {
            int p = pos - 1 + d;
            if (p < 0 || p > 255) continue;
            float cz = p * (7.0f / 255.0f);
            int i0 = (int)floorf(cz); i0 = min(max(i0, 0), 7);
            int i1 = min(i0 + 1, 7);
            float f = cz - (float)i0;
            float pv = params[c * 8 + i0];
            pv += (params[c * 8 + i1] - pv) * f;
            a += dww[c * 3 + d] * pv;
        }
        g[c] = gelu_f(a);
    }
#pragma unroll
    for (int co = 0; co < 32; ++co) {
        float a = pwb[co];
#pragma unroll
        for (int ci = 0; ci < 32; ++ci) a += pww[co * 32 + ci] * g[ci];
        att[co * 256 + pos] = a;
    }
}

// -------------------------------------------- pw fp32 -> bf16 [co][ci] ----
__global__ void convert_pw_kernel(const float* __restrict__ pw, unsigned short* __restrict__ pwb16) {
    int i = blockIdx.x * 256 + threadIdx.x;
    pwb16[i] = f2bf(pw[i]);
}

// ---------------------------------------------------------- fused main ----
// LN1 -> {att multiplies | pw+gelu+dw3x3 on x4} -> LN2 + residual -> z
#define TH_C 4
__global__ __launch_bounds__(1024, 8) void fused_main_kernel(
    const float* __restrict__ x,
    const float* __restrict__ n1w, const float* __restrict__ n1b,
    const float* __restrict__ dw_pw_w, const float* __restrict__ dw_pw_b,
    const float* __restrict__ dw_dw_w, const float* __restrict__ dw_dw_b,
    const float* __restrict__ n2w, const float* __restrict__ n2b,
    const float* __restrict__ att_xy, const float* __restrict__ att_zx,
    const float* __restrict__ att_zy,
    float* __restrict__ zout)
{
    __shared__ unsigned short g4[3][32][256];   // 48 KB bf16 ring: gelu(pw(x4)) rows
    __shared__ float red_s[4][256];
    __shared__ float red_q[4][256];

    const int b     = blockIdx.x >> 6;
    const int h0    = (blockIdx.x & 63) * TH_C;
    const int chunk = threadIdx.x >> 8;          // 0..3  -> channels [32c,32c+32)
    const int w     = threadIdx.x & 255;
    const int cbase = chunk * 32;

    float xn[2][32];   // LN1 output double buffer (static-indexed via full unroll)
    float tmp[32];     // scratch: x values during load, y values during emit

#pragma unroll
    for (int rr = -1; rr <= TH_C; ++rr) {
        const int h    = h0 + rr;
        const int slot = (rr + 1) % 3;
        const int cur  = (rr + 1) & 1;
        const bool hv  = (h >= 0) && (h < HH);   // block-uniform

        // ---- load row h, LN1 stats ----
        float s1 = 0.f, s2 = 0.f;
        if (hv) {
            const float* xp = x + (((size_t)b * NC + cbase) * HH + h) * WW + w;
#pragma unroll
            for (int k = 0; k < 32; ++k) {
                float v = xp[(size_t)k * 65536];
                tmp[k] = v; s1 += v; s2 += v * v;
            }
        }
        red_s[chunk][w] = s1;
        red_q[chunk][w] = s2;
        __syncthreads();
        {
            float ssum = red_s[0][w] + red_s[1][w] + red_s[2][w] + red_s[3][w];
            float qsum = red_q[0][w] + red_q[1][w] + red_q[2][w] + red_q[3][w];
            float mean = ssum * (1.f / 128.f);
            float var  = qsum * (1.f / 128.f) - mean * mean;
            float rstd = rsqrtf(var + 1e-6f);
            if (hv) {
#pragma unroll
                for (int k = 0; k < 32; ++k) {
                    int c = cbase + k;
                    xn[cur][k] = (tmp[k] - mean) * rstd * n1w[c] + n1b[c];
                }
            }
        }
        // ---- g4 row: gelu(pw(x4)) (chunk 3 only), or zero-pad row ----
        if (hv) {
            if (chunk == 3) {
#pragma unroll
                for (int co = 0; co < 32; ++co) {
                    float a = dw_pw_b[co];
#pragma unroll
                    for (int k = 0; k < 32; ++k) a += dw_pw_w[co * 32 + k] * xn[cur][k];
                    g4[slot][co][w] = f2bf(gelu_f(a));
                }
            }
        } else {
#pragma unroll
            for (int j = 0; j < 8; ++j) g4[slot][chunk * 8 + j][w] = 0;
        }
        __syncthreads();

        // ---- emit row he = h-1 ----
        if (rr >= 1) {
            const int he = h - 1;
            const int pv = rr & 1;
            float e1 = 0.f, e2 = 0.f;
            if (chunk == 0) {
                const float* ap = att_xy + he * WW + w;
#pragma unroll
                for (int k = 0; k < 32; ++k) {
                    float yv = xn[pv][k] * ap[(size_t)k * 65536];
                    tmp[k] = yv; e1 += yv; e2 += yv * yv;
                }
            } else if (chunk == 1) {
#pragma unroll
                for (int k = 0; k < 32; ++k) {
                    float yv = xn[pv][k] * att_zx[k * 256 + he];
                    tmp[k] = yv; e1 += yv; e2 += yv * yv;
                }
            } else if (chunk == 2) {
#pragma unroll
                for (int k = 0; k < 32; ++k) {
                    float yv = xn[pv][k] * att_zy[k * 256 + w];
                    tmp[k] = yv; e1 += yv; e2 += yv * yv;
                }
            } else {
                const int sa = (rr - 1) % 3, sb = rr % 3, sc = (rr + 1) % 3;
#pragma unroll
                for (int k = 0; k < 32; ++k) {
                    float a = dw_dw_b[k];
                    const float* wk = dw_dw_w + k * 9;
                    {
                        const unsigned short* gr = &g4[sa][k][0];
                        if (w > 0)   a += wk[0] * bf2f(gr[w - 1]);
                                     a += wk[1] * bf2f(gr[w]);
                        if (w < 255) a += wk[2] * bf2f(gr[w + 1]);
                    }
                    {
                        const unsigned short* gr = &g4[sb][k][0];
                        if (w > 0)   a += wk[3] * bf2f(gr[w - 1]);
                                     a += wk[4] * bf2f(gr[w]);
                        if (w < 255) a += wk[5] * bf2f(gr[w + 1]);
                    }
                    {
                        const unsigned short* gr = &g4[sc][k][0];
                        if (w > 0)   a += wk[6] * bf2f(gr[w - 1]);
                                     a += wk[7] * bf2f(gr[w]);
                        if (w < 255) a += wk[8] * bf2f(gr[w + 1]);
                    }
                    tmp[k] = a; e1 += a; e2 += a * a;
                }
            }
            red_s[chunk][w] = e1;
            red_q[chunk][w] = e2;
            __syncthreads();
            float ssum = red_s[0][w] + red_s[1][w] + red_s[2][w] + red_s[3][w];
            float qsum = red_q[0][w] + red_q[1][w] + red_q[2][w] + red_q[3][w];
            float mean = ssum * (1.f / 128.f);
            float var  = qsum * (1.f / 128.f) - mean * mean;
            float rstd = rsqrtf(var + 1e-6f);
            float* zp = zout + (((size_t)b * NC + cbase) * HH + he) * WW + w;
#pragma unroll
            for (int k = 0; k < 32; ++k) {
                int c = cbase + k;
                zp[(size_t)k * 65536] = (tmp[k] - mean) * rstd * n2w[c] + n2b[c] + xn[pv][k];
            }
            __syncthreads();
        }
    }
}

// --------------------------------------------------------------- ldw ----
// z -> depthwise 3x3 -> gelu -> bf16 LDS tile -> MFMA 1x1 conv 128->128 -> out
// Block: 256 thr (4 waves), tile (b, h, 64 px) x 128 co. LDS 16 KB -> 8 blocks/CU.
__global__ __launch_bounds__(256, 8) void ldw_kernel(
    const float* __restrict__ z, const float* __restrict__ dww,
    const float* __restrict__ dwb, const unsigned short* __restrict__ wb16,
    const float* __restrict__ pwb, float* __restrict__ out)
{
    // swizzled bf16 t[64 px][128 ci]; 16B chunk index ^= (px & 15)
    __shared__ __align__(16) unsigned short tl[64 * 128];   // 16 KB

    // XCD-chunked bijective swizzle: 4096 blocks, 8 XCDs
    const int lid  = (blockIdx.x & 7) * 512 + (blockIdx.x >> 3);
    const int b    = lid >> 10;
    const int h    = (lid >> 2) & 255;
    const int px0  = (lid & 3) * 64;

    const int tid  = threadIdx.x;
    const int lane = tid & 63;
    const int wv   = tid >> 6;       // wave -> co base wv*32
    const int l15  = lane & 15;
    const int l4   = lane >> 4;

    // ---- A fragments (W[co][ci] bf16) + bias: issue loads early ----
    short8v afrag[2][4];
#pragma unroll
    for (int ct = 0; ct < 2; ++ct) {
        const int co = wv * 32 + ct * 16 + l15;
#pragma unroll
        for (int ks = 0; ks < 4; ++ks)
            afrag[ct][ks] = *(const short8v*)(wb16 + co * 128 + ks * 32 + l4 * 8);
    }
    float4v bias[2];
#pragma unroll
    for (int ct = 0; ct < 2; ++ct) {
        const float4 bv = *(const float4*)(pwb + wv * 32 + ct * 16 + l4 * 4);
        bias[ct] = float4v{bv.x, bv.y, bv.z, bv.w};
    }

    // ---- phase 1: depthwise 3x3 + gelu -> swizzled bf16 LDS ----
    {
        const int px = lane;            // 0..63 within strip
        const int w  = px0 + px;
        const int cibase = wv * 32;
        char* tlb = (char*)tl;
#pragma unroll
        for (int k = 0; k < 32; k += 2) {
            float tv[2];
#pragma unroll
            for (int j = 0; j < 2; ++j) {
                const int c = cibase + k + j;
                const float* wk = dww + c * 9;
                float a = dwb[c];
                const float* zc = z + ((size_t)(b * NC + c)) * 65536;
#pragma unroll
                for (int dy = -1; dy <= 1; ++dy) {
                    int hy = h + dy;
                    if (hy < 0 || hy > 255) continue;
                    const float* zr = zc + hy * WW;
                    const float* wr = wk + (dy + 1) * 3;
                    if (w > 0)   a += wr[0] * zr[w - 1];
                                 a += wr[1] * zr[w];
                    if (w < 255) a += wr[2] * zr[w + 1];
                }
                tv[j] = gelu_f(a);
            }
            const int ci = cibase + k;
            const int chunk = (ci >> 3) ^ (px & 15);
            unsigned pack = (unsigned)f2bf(tv[0]) | ((unsigned)f2bf(tv[1]) << 16);
            *(unsigned*)(tlb + px * 256 + chunk * 16 + (ci & 7) * 2) = pack;
        }
    }
    __syncthreads();

    // ---- phase 2: MFMA 1x1 conv, wave wv owns co [wv*32, wv*32+32) x 64 px ----
    const char* tlb = (const char*)tl;
#pragma unroll
    for (int pt = 0; pt < 4; ++pt) {
        const int px = pt * 16 + l15;
        short8v bfrag[4];
#pragma unroll
        for (int ks = 0; ks < 4; ++ks) {
            const int chunk = (ks * 4 + l4) ^ (px & 15);
            bfrag[ks] = *(const short8v*)(tlb + px * 256 + chunk * 16);
        }
        float4v acc0 = bias[0];
        float4v acc1 = bias[1];
#pragma unroll
        for (int ks = 0; ks < 4; ++ks) {
            acc0 = __builtin_amdgcn_mfma_f32_16x16x32_bf16(afrag[0][ks], bfrag[ks], acc0, 0, 0, 0);
            acc1 = __builtin_amdgcn_mfma_f32_16x16x32_bf16(afrag[1][ks], bfrag[ks], acc1, 0, 0, 0);
        }
        // store: D col = lane&15 (px), row = 4*(lane>>4)+reg (co)
#pragma unroll
        for (int ct = 0; ct < 2; ++ct) {
            const int co = wv * 32 + ct * 16 + l4 * 4;
            float* op = out + ((size_t)(b * NC + co)) * 65536 + h * WW + px0 + pt * 16 + l15;
            const float4v av = ct ? acc1 : acc0;
#pragma unroll
            for (int r = 0; r < 4; ++r) op[(size_t)r * 65536] = av[r];
        }
    }
}

// ------------------------------------------------------------- launch ----
extern "C" void kernel_launch(void* const* d_in, const int* in_sizes, int n_in,
                              void* d_out, int out_size, void* d_ws, size_t ws_size,
                              hipStream_t stream)
{
    (void)in_sizes; (void)n_in; (void)out_size; (void)ws_size;
    const float* x       = (const float*)d_in[0];
    const float* n1w     = (const float*)d_in[1];
    const float* n1b     = (const float*)d_in[2];
    const float* pxy     = (const float*)d_in[3];
    const float* cxy_dww = (const float*)d_in[4];
    const float* cxy_dwb = (const float*)d_in[5];
    const float* cxy_pww = (const float*)d_in[6];
    const float* cxy_pwb = (const float*)d_in[7];
    const float* pzx     = (const float*)d_in[8];
    const float* czx_dww = (const float*)d_in[9];
    const float* czx_dwb = (const float*)d_in[10];
    const float* czx_pww = (const float*)d_in[11];
    const float* czx_pwb = (const float*)d_in[12];
    const float* pzy     = (const float*)d_in[13];
    const float* czy_dww = (const float*)d_in[14];
    const float* czy_dwb = (const float*)d_in[15];
    const float* czy_pww = (const float*)d_in[16];
    const float* czy_pwb = (const float*)d_in[17];
    const float* dw_pww  = (const float*)d_in[18];
    const float* dw_pwb  = (const float*)d_in[19];
    const float* dw_dww  = (const float*)d_in[20];
    const float* dw_dwb  = (const float*)d_in[21];
    const float* n2w     = (const float*)d_in[22];
    const float* n2b     = (const float*)d_in[23];
    const float* ldw_dww = (const float*)d_in[24];
    const float* ldw_dwb = (const float*)d_in[25];
    const float* ldw_pww = (const float*)d_in[26];
    const float* ldw_pwb = (const float*)d_in[27];
    float* out = (float*)d_out;
    char* ws   = (char*)d_ws;

    float* att_xy = (float*)ws;                                   // 8 MiB
    float* att_zx = att_xy + 32 * 65536;
    float* att_zy = att_zx + 32 * 256;
    unsigned short* pwb16 = (unsigned short*)(att_zy + 32 * 256); // 32 KB
    float* zbuf   = (float*)(ws + ((32 * 65536 + 2 * 32 * 256) * 4 + 128 * 128 * 2 + 255) / 256 * 256);

    attxy_kernel<<<256, 256, 0, stream>>>(pxy, cxy_dww, cxy_dwb, cxy_pww, cxy_pwb, att_xy);
    attz_kernel<<<2, 256, 0, stream>>>(pzx, czx_dww, czx_dwb, czx_pww, czx_pwb,
                                       pzy, czy_dww, czy_dwb, czy_pww, czy_pwb,
                                       att_zx, att_zy);
    convert_pw_kernel<<<64, 256, 0, stream>>>(ldw_pww, pwb16);
    fused_main_kernel<<<256, 1024, 0, stream>>>(x, n1w, n1b, dw_pww, dw_pwb, dw_dww, dw_dwb,
                                                n2w, n2b, att_xy, att_zx, att_zy, zbuf);
    ldw_kernel<<<4096, 256, 0, stream>>>(zbuf, ldw_dww, ldw_dwb, pwb16, ldw_pwb, out);
}

// Round 4
// 654.950 us; speedup vs baseline: 3.0144x; 1.4551x over previous
//
#include <hip/hip_runtime.h>
#include <hip/hip_bf16.h>
#include <math.h>

#define HH 256
#define WW 256
#define NB 4
#define NC 128
#define C4 32

typedef __attribute__((ext_vector_type(8))) short short8v;
typedef __attribute__((ext_vector_type(4))) float float4v;
typedef unsigned short ushort_t;

__device__ __forceinline__ float gelu_f(float v) {
    return 0.5f * v * (1.0f + erff(v * 0.7071067811865476f));
}
__device__ __forceinline__ unsigned short f2bf(float x) {
    __hip_bfloat16 h = __float2bfloat16(x);
    return __builtin_bit_cast(unsigned short, h);
}
__device__ __forceinline__ float bf2f(unsigned short u) {
    return __uint_as_float(((unsigned)u) << 16);
}

// ---------------------------------------------------------------- att_xy ----
__global__ void attxy_kernel(const float* __restrict__ params,
                             const float* __restrict__ dww, const float* __restrict__ dwb,
                             const float* __restrict__ pww, const float* __restrict__ pwb,
                             float* __restrict__ att)
{
    __shared__ float P[2048];
    __shared__ float DW[288];
    __shared__ float PW[1024];
    for (int i = threadIdx.x; i < 2048; i += 256) P[i] = params[i];
    for (int i = threadIdx.x; i < 288;  i += 256) DW[i] = dww[i];
    for (int i = threadIdx.x; i < 1024; i += 256) PW[i] = pww[i];
    __syncthreads();
    const int idx = blockIdx.x * 256 + threadIdx.x;
    const int h = idx >> 8, w = idx & 255;

    int iy0[3], iy1[3], ix0[3], ix1[3];
    float fy[3], fx[3];
    bool vy[3], vx[3];
#pragma unroll
    for (int d = 0; d < 3; ++d) {
        int hh = h - 1 + d;
        vy[d] = (hh >= 0 && hh < HH);
        float cy = hh * (7.0f / 255.0f);
        int i0 = (int)floorf(cy); i0 = min(max(i0, 0), 7);
        iy0[d] = i0; iy1[d] = min(i0 + 1, 7); fy[d] = cy - (float)i0;
        int ww2 = w - 1 + d;
        vx[d] = (ww2 >= 0 && ww2 < WW);
        float cx = ww2 * (7.0f / 255.0f);
        int j0 = (int)floorf(cx); j0 = min(max(j0, 0), 7);
        ix0[d] = j0; ix1[d] = min(j0 + 1, 7); fx[d] = cx - (float)j0;
    }
    float g[32];
#pragma unroll
    for (int c = 0; c < 32; ++c) {
        float a = dwb[c];
        const float* Pc = P + c * 64;
#pragma unroll
        for (int dy = 0; dy < 3; ++dy) {
            if (!vy[dy]) continue;
#pragma unroll
            for (int dx = 0; dx < 3; ++dx) {
                if (!vx[dx]) continue;
                float p00 = Pc[iy0[dy] * 8 + ix0[dx]];
                float p01 = Pc[iy0[dy] * 8 + ix1[dx]];
                float p10 = Pc[iy1[dy] * 8 + ix0[dx]];
                float p11 = Pc[iy1[dy] * 8 + ix1[dx]];
                float pt = p00 + (p01 - p00) * fx[dx];
                float pb = p10 + (p11 - p10) * fx[dx];
                float p  = pt + (pb - pt) * fy[dy];
                a += DW[c * 9 + dy * 3 + dx] * p;
            }
        }
        g[c] = gelu_f(a);
    }
#pragma unroll
    for (int co = 0; co < 32; ++co) {
        float a = pwb[co];
#pragma unroll
        for (int c = 0; c < 32; ++c) a += PW[co * 32 + c] * g[c];
        att[co * 65536 + idx] = a;
    }
}

// ------------------------------------------------------------ att_zx/zy ----
__global__ void attz_kernel(const float* __restrict__ params_zx, const float* __restrict__ zx_dww,
                            const float* __restrict__ zx_dwb, const float* __restrict__ zx_pww,
                            const float* __restrict__ zx_pwb,
                            const float* __restrict__ params_zy, const float* __restrict__ zy_dww,
                            const float* __restrict__ zy_dwb, const float* __restrict__ zy_pww,
                            const float* __restrict__ zy_pwb,
                            float* __restrict__ att_zx, float* __restrict__ att_zy)
{
    const bool sel = (blockIdx.x != 0);
    const float* params = sel ? params_zy : params_zx;
    const float* dww = sel ? zy_dww : zx_dww;
    const float* dwb = sel ? zy_dwb : zx_dwb;
    const float* pww = sel ? zy_pww : zx_pww;
    const float* pwb = sel ? zy_pwb : zx_pwb;
    float* att = sel ? att_zy : att_zx;
    const int pos = threadIdx.x;
    float g[32];
#pragma unroll
    for (int c = 0; c < 32; ++c) {
        float a = dwb[c];
#pragma unroll
        for (int d = 0; d < 3; ++d) {
            int p = pos - 1 + d;
            if (p < 0 || p > 255) continue;
            float cz = p * (7.0f / 255.0f);
            int i0 = (int)floorf(cz); i0 = min(max(i0, 0), 7);
            int i1 = min(i0 + 1, 7);
            float f = cz - (float)i0;
            float pv = params[c * 8 + i0];
            pv += (params[c * 8 + i1] - pv) * f;
            a += dww[c * 3 + d] * pv;
        }
        g[c] = gelu_f(a);
    }
#pragma unroll
    for (int co = 0; co < 32; ++co) {
        float a = pwb[co];
#pragma unroll
        for (int ci = 0; ci < 32; ++ci) a += pww[co * 32 + ci] * g[ci];
        att[co * 256 + pos] = a;
    }
}

// -------------------------------------------- pw fp32 -> bf16 [co][ci] ----
__global__ void convert_pw_kernel(const float* __restrict__ pw, ushort_t* __restrict__ pwb16) {
    int i = blockIdx.x * 256 + threadIdx.x;
    pwb16[i] = f2bf(pw[i]);
}

// ------------------------------------------------------------- K1: ln1pw ----
// thread = 1 pixel. LN1 stats over 128 ch; keep x4 chunk; pw 32x32 + gelu -> g bf16
__global__ __launch_bounds__(256) void ln1pw_kernel(
    const float* __restrict__ x,
    const float* __restrict__ n1w, const float* __restrict__ n1b,
    const float* __restrict__ pww, const float* __restrict__ pwb,
    ushort_t* __restrict__ g)
{
    const int b = blockIdx.x >> 8, h = blockIdx.x & 255, w = threadIdx.x;
    const float* xp = x + (((size_t)b * NC) * HH + h) * WW + w;
    float s1 = 0.f, s2 = 0.f;
    float x4v[32];
#pragma unroll
    for (int k = 0; k < 96; ++k) {
        float v = xp[(size_t)k * 65536];
        s1 += v; s2 += v * v;
    }
#pragma unroll
    for (int j = 0; j < 32; ++j) {
        float v = xp[(size_t)(96 + j) * 65536];
        x4v[j] = v; s1 += v; s2 += v * v;
    }
    float m = s1 * (1.f / 128.f);
    float r = rsqrtf(s2 * (1.f / 128.f) - m * m + 1e-6f);
#pragma unroll
    for (int j = 0; j < 32; ++j)
        x4v[j] = (x4v[j] - m) * r * n1w[96 + j] + n1b[96 + j];

    ushort_t* gp = g + (((size_t)b * 32) * HH + h) * WW + w;
#pragma unroll
    for (int co = 0; co < 32; ++co) {
        float a = pwb[co];
#pragma unroll
        for (int j = 0; j < 32; ++j) a += pww[co * 32 + j] * x4v[j];
        gp[(size_t)co * 65536] = f2bf(gelu_f(a));
    }
}

// ------------------------------------------------------------- K2: apply ----
// thread = 1 pixel. Recompute LN1 on the fly; u = attn-multiplied / dw3x3(g);
// LN2 + residual -> z bf16.
__global__ __launch_bounds__(256) void apply_kernel(
    const float* __restrict__ x,
    const float* __restrict__ n1w, const float* __restrict__ n1b,
    const float* __restrict__ n2w, const float* __restrict__ n2b,
    const float* __restrict__ att_xy, const float* __restrict__ att_zx,
    const float* __restrict__ att_zy,
    const ushort_t* __restrict__ g,
    const float* __restrict__ dww, const float* __restrict__ dwb,
    ushort_t* __restrict__ z)
{
    const int b = blockIdx.x >> 8, h = blockIdx.x & 255, w = threadIdx.x;
    const size_t base = (((size_t)b * NC) * HH + h) * WW + w;
    const int pix = h * WW + w;

    // ---- pass 0: LN1 stats ----
    float s1 = 0.f, s2 = 0.f;
#pragma unroll
    for (int k = 0; k < 128; ++k) {
        float v = x[base + (size_t)k * 65536];
        s1 += v; s2 += v * v;
    }
    const float m1 = s1 * (1.f / 128.f);
    const float r1 = rsqrtf(s2 * (1.f / 128.f) - m1 * m1 + 1e-6f);
    asm volatile("" ::: "memory");   // don't keep 128 loads live across passes

    // ---- pass 1: u stats (LN2 input) ----
    float e1 = 0.f, e2 = 0.f;
#pragma unroll
    for (int k = 0; k < 32; ++k) {
        float xn = (x[base + (size_t)k * 65536] - m1) * r1 * n1w[k] + n1b[k];
        float u = xn * att_xy[(size_t)k * 65536 + pix];
        e1 += u; e2 += u * u;
    }
#pragma unroll
    for (int k = 0; k < 32; ++k) {
        float xn = (x[base + (size_t)(32 + k) * 65536] - m1) * r1 * n1w[32 + k] + n1b[32 + k];
        float u = xn * att_zx[k * 256 + h];     // wave-uniform -> s_load
        e1 += u; e2 += u * u;
    }
#pragma unroll
    for (int k = 0; k < 32; ++k) {
        float xn = (x[base + (size_t)(64 + k) * 65536] - m1) * r1 * n1w[64 + k] + n1b[64 + k];
        float u = xn * att_zy[k * 256 + w];
        e1 += u; e2 += u * u;
    }
    float u4[32];
#pragma unroll
    for (int j = 0; j < 32; ++j) {
        float a = dwb[j];
        const ushort_t* gc = g + (((size_t)b * 32 + j) * HH) * WW + w;
#pragma unroll
        for (int dy = -1; dy <= 1; ++dy) {
            int hy = h + dy;
            if (hy < 0 || hy > 255) continue;   // uniform per block
            const ushort_t* rp = gc + (size_t)hy * WW;
            const float* wr = dww + j * 9 + (dy + 1) * 3;
            if (w > 0)   a += wr[0] * bf2f(rp[-1]);
                         a += wr[1] * bf2f(rp[0]);
            if (w < 255) a += wr[2] * bf2f(rp[1]);
        }
        u4[j] = a; e1 += a; e2 += a * a;
    }
    const float m2 = e1 * (1.f / 128.f);
    const float r2 = rsqrtf(e2 * (1.f / 128.f) - m2 * m2 + 1e-6f);
    asm volatile("" ::: "memory");

    // ---- pass 2: emit z = LN2(u) + xn ----
#pragma unroll
    for (int k = 0; k < 32; ++k) {
        float xn = (x[base + (size_t)k * 65536] - m1) * r1 * n1w[k] + n1b[k];
        float u = xn * att_xy[(size_t)k * 65536 + pix];
        z[base + (size_t)k * 65536] = f2bf((u - m2) * r2 * n2w[k] + n2b[k] + xn);
    }
#pragma unroll
    for (int k = 0; k < 32; ++k) {
        int c = 32 + k;
        float xn = (x[base + (size_t)c * 65536] - m1) * r1 * n1w[c] + n1b[c];
        float u = xn * att_zx[k * 256 + h];
        z[base + (size_t)c * 65536] = f2bf((u - m2) * r2 * n2w[c] + n2b[c] + xn);
    }
#pragma unroll
    for (int k = 0; k < 32; ++k) {
        int c = 64 + k;
        float xn = (x[base + (size_t)c * 65536] - m1) * r1 * n1w[c] + n1b[c];
        float u = xn * att_zy[k * 256 + w];
        z[base + (size_t)c * 65536] = f2bf((u - m2) * r2 * n2w[c] + n2b[c] + xn);
    }
#pragma unroll
    for (int j = 0; j < 32; ++j) {
        int c = 96 + j;
        float xn = (x[base + (size_t)c * 65536] - m1) * r1 * n1w[c] + n1b[c];
        z[base + (size_t)c * 65536] = f2bf((u4[j] - m2) * r2 * n2w[c] + n2b[c] + xn);
    }
}

// --------------------------------------------------------------- ldw ----
// z (bf16) -> depthwise 3x3 -> gelu -> bf16 LDS tile -> MFMA 1x1 128->128 -> out
__global__ __launch_bounds__(256, 4) void ldw_kernel(
    const ushort_t* __restrict__ z, const float* __restrict__ dww,
    const float* __restrict__ dwb, const ushort_t* __restrict__ wb16,
    const float* __restrict__ pwb, float* __restrict__ out)
{
    // swizzled bf16 t[64 px][128 ci]; 16B chunk index ^= (px & 15)
    __shared__ __align__(16) ushort_t tl[64 * 128];   // 16 KB

    // XCD-chunked bijective swizzle: 4096 blocks, 8 XCDs
    const int lid  = (blockIdx.x & 7) * 512 + (blockIdx.x >> 3);
    const int b    = lid >> 10;
    const int h    = (lid >> 2) & 255;
    const int px0  = (lid & 3) * 64;

    const int tid  = threadIdx.x;
    const int lane = tid & 63;
    const int wv   = tid >> 6;       // wave -> co base wv*32
    const int l15  = lane & 15;
    const int l4   = lane >> 4;

    // ---- A fragments (W[co][ci] bf16) + bias ----
    short8v afrag[2][4];
#pragma unroll
    for (int ct = 0; ct < 2; ++ct) {
        const int co = wv * 32 + ct * 16 + l15;
#pragma unroll
        for (int ks = 0; ks < 4; ++ks)
            afrag[ct][ks] = *(const short8v*)(wb16 + co * 128 + ks * 32 + l4 * 8);
    }
    float4v bias[2];
#pragma unroll
    for (int ct = 0; ct < 2; ++ct) {
        const float4 bv = *(const float4*)(pwb + wv * 32 + ct * 16 + l4 * 4);
        bias[ct] = float4v{bv.x, bv.y, bv.z, bv.w};
    }

    // ---- phase 1: depthwise 3x3 + gelu -> swizzled bf16 LDS ----
    {
        const int px = lane;
        const int w  = px0 + px;
        const int cibase = wv * 32;
        char* tlb = (char*)tl;
#pragma unroll
        for (int k = 0; k < 32; k += 2) {
            float tv[2];
#pragma unroll
            for (int j = 0; j < 2; ++j) {
                const int c = cibase + k + j;
                const float* wk = dww + c * 9;
                float a = dwb[c];
                const ushort_t* zc = z + ((size_t)(b * NC + c)) * 65536;
#pragma unroll
                for (int dy = -1; dy <= 1; ++dy) {
                    int hy = h + dy;
                    if (hy < 0 || hy > 255) continue;
                    const ushort_t* zr = zc + hy * WW;
                    const float* wr = wk + (dy + 1) * 3;
                    if (w > 0)   a += wr[0] * bf2f(zr[w - 1]);
                                 a += wr[1] * bf2f(zr[w]);
                    if (w < 255) a += wr[2] * bf2f(zr[w + 1]);
                }
                tv[j] = gelu_f(a);
            }
            const int ci = cibase + k;
            const int chunk = (ci >> 3) ^ (px & 15);
            unsigned pack = (unsigned)f2bf(tv[0]) | ((unsigned)f2bf(tv[1]) << 16);
            *(unsigned*)(tlb + px * 256 + chunk * 16 + (ci & 7) * 2) = pack;
        }
    }
    __syncthreads();

    // ---- phase 2: MFMA 1x1 conv ----
    const char* tlb = (const char*)tl;
#pragma unroll
    for (int pt = 0; pt < 4; ++pt) {
        const int px = pt * 16 + l15;
        short8v bfrag[4];
#pragma unroll
        for (int ks = 0; ks < 4; ++ks) {
            const int chunk = (ks * 4 + l4) ^ (px & 15);
            bfrag[ks] = *(const short8v*)(tlb + px * 256 + chunk * 16);
        }
        float4v acc0 = bias[0];
        float4v acc1 = bias[1];
#pragma unroll
        for (int ks = 0; ks < 4; ++ks) {
            acc0 = __builtin_amdgcn_mfma_f32_16x16x32_bf16(afrag[0][ks], bfrag[ks], acc0, 0, 0, 0);
            acc1 = __builtin_amdgcn_mfma_f32_16x16x32_bf16(afrag[1][ks], bfrag[ks], acc1, 0, 0, 0);
        }
#pragma unroll
        for (int ct = 0; ct < 2; ++ct) {
            const int co = wv * 32 + ct * 16 + l4 * 4;
            float* op = out + ((size_t)(b * NC + co)) * 65536 + h * WW + px0 + pt * 16 + l15;
            const float4v av = ct ? acc1 : acc0;
#pragma unroll
            for (int r = 0; r < 4; ++r) op[(size_t)r * 65536] = av[r];
        }
    }
}

// ------------------------------------------------------------- launch ----
extern "C" void kernel_launch(void* const* d_in, const int* in_sizes, int n_in,
                              void* d_out, int out_size, void* d_ws, size_t ws_size,
                              hipStream_t stream)
{
    (void)in_sizes; (void)n_in; (void)out_size; (void)ws_size;
    const float* x       = (const float*)d_in[0];
    const float* n1w     = (const float*)d_in[1];
    const float* n1b     = (const float*)d_in[2];
    const float* pxy     = (const float*)d_in[3];
    const float* cxy_dww = (const float*)d_in[4];
    const float* cxy_dwb = (const float*)d_in[5];
    const float* cxy_pww = (const float*)d_in[6];
    const float* cxy_pwb = (const float*)d_in[7];
    const float* pzx     = (const float*)d_in[8];
    const float* czx_dww = (const float*)d_in[9];
    const float* czx_dwb = (const float*)d_in[10];
    const float* czx_pww = (const float*)d_in[11];
    const float* czx_pwb = (const float*)d_in[12];
    const float* pzy     = (const float*)d_in[13];
    const float* czy_dww = (const float*)d_in[14];
    const float* czy_dwb = (const float*)d_in[15];
    const float* czy_pww = (const float*)d_in[16];
    const float* czy_pwb = (const float*)d_in[17];
    const float* dw_pww  = (const float*)d_in[18];
    const float* dw_pwb  = (const float*)d_in[19];
    const float* dw_dww  = (const float*)d_in[20];
    const float* dw_dwb  = (const float*)d_in[21];
    const float* n2w     = (const float*)d_in[22];
    const float* n2b     = (const float*)d_in[23];
    const float* ldw_dww = (const float*)d_in[24];
    const float* ldw_dwb = (const float*)d_in[25];
    const float* ldw_pww = (const float*)d_in[26];
    const float* ldw_pwb = (const float*)d_in[27];
    float* out = (float*)d_out;
    char* ws   = (char*)d_ws;

    // ws layout (bytes): att_xy f32 8MB | att_zx f32 32KB | att_zy f32 32KB |
    //                    pwb16 u16 32KB | g u16 16MB | zb u16 64MB   (~88 MB)
    float* att_xy = (float*)ws;
    float* att_zx = att_xy + 32 * 65536;
    float* att_zy = att_zx + 32 * 256;
    ushort_t* pwb16 = (ushort_t*)(att_zy + 32 * 256);
    ushort_t* gbuf  = pwb16 + 128 * 128;
    ushort_t* zbuf  = gbuf + (size_t)4 * 32 * 65536;

    attxy_kernel<<<256, 256, 0, stream>>>(pxy, cxy_dww, cxy_dwb, cxy_pww, cxy_pwb, att_xy);
    attz_kernel<<<2, 256, 0, stream>>>(pzx, czx_dww, czx_dwb, czx_pww, czx_pwb,
                                       pzy, czy_dww, czy_dwb, czy_pww, czy_pwb,
                                       att_zx, att_zy);
    convert_pw_kernel<<<64, 256, 0, stream>>>(ldw_pww, pwb16);
    ln1pw_kernel<<<1024, 256, 0, stream>>>(x, n1w, n1b, dw_pww, dw_pwb, gbuf);
    apply_kernel<<<1024, 256, 0, stream>>>(x, n1w, n1b, n2w, n2b,
                                           att_xy, att_zx, att_zy,
                                           gbuf, dw_dww, dw_dwb, zbuf);
    ldw_kernel<<<4096, 256, 0, stream>>>(zbuf, ldw_dww, ldw_dwb, pwb16, ldw_pwb, out);
}

// Round 5
// 442.183 us; speedup vs baseline: 4.4649x; 1.4812x over previous
//
#include <hip/hip_runtime.h>
#include <hip/hip_bf16.h>
#include <math.h>

#define HH 256
#define WW 256
#define NB 4
#define NC 128
#define C4 32

typedef __attribute__((ext_vector_type(8))) short short8v;
typedef __attribute__((ext_vector_type(4))) float float4v;
typedef unsigned short ushort_t;

__device__ __forceinline__ float gelu_f(float v) {
    return 0.5f * v * (1.0f + erff(v * 0.7071067811865476f));
}
__device__ __forceinline__ unsigned short f2bf(float x) {
    __hip_bfloat16 h = __float2bfloat16(x);
    return __builtin_bit_cast(unsigned short, h);
}
__device__ __forceinline__ float bf2f(unsigned short u) {
    return __uint_as_float(((unsigned)u) << 16);
}

// ---------------------------------------------------------------- att_xy ----
__global__ void attxy_kernel(const float* __restrict__ params,
                             const float* __restrict__ dww, const float* __restrict__ dwb,
                             const float* __restrict__ pww, const float* __restrict__ pwb,
                             float* __restrict__ att)
{
    __shared__ float P[2048];
    __shared__ float DW[288];
    __shared__ float PW[1024];
    for (int i = threadIdx.x; i < 2048; i += 256) P[i] = params[i];
    for (int i = threadIdx.x; i < 288;  i += 256) DW[i] = dww[i];
    for (int i = threadIdx.x; i < 1024; i += 256) PW[i] = pww[i];
    __syncthreads();
    const int idx = blockIdx.x * 256 + threadIdx.x;
    const int h = idx >> 8, w = idx & 255;

    int iy0[3], iy1[3], ix0[3], ix1[3];
    float fy[3], fx[3];
    bool vy[3], vx[3];
#pragma unroll
    for (int d = 0; d < 3; ++d) {
        int hh = h - 1 + d;
        vy[d] = (hh >= 0 && hh < HH);
        float cy = hh * (7.0f / 255.0f);
        int i0 = (int)floorf(cy); i0 = min(max(i0, 0), 7);
        iy0[d] = i0; iy1[d] = min(i0 + 1, 7); fy[d] = cy - (float)i0;
        int ww2 = w - 1 + d;
        vx[d] = (ww2 >= 0 && ww2 < WW);
        float cx = ww2 * (7.0f / 255.0f);
        int j0 = (int)floorf(cx); j0 = min(max(j0, 0), 7);
        ix0[d] = j0; ix1[d] = min(j0 + 1, 7); fx[d] = cx - (float)j0;
    }
    float g[32];
#pragma unroll
    for (int c = 0; c < 32; ++c) {
        float a = dwb[c];
        const float* Pc = P + c * 64;
#pragma unroll
        for (int dy = 0; dy < 3; ++dy) {
            if (!vy[dy]) continue;
#pragma unroll
            for (int dx = 0; dx < 3; ++dx) {
                if (!vx[dx]) continue;
                float p00 = Pc[iy0[dy] * 8 + ix0[dx]];
                float p01 = Pc[iy0[dy] * 8 + ix1[dx]];
                float p10 = Pc[iy1[dy] * 8 + ix0[dx]];
                float p11 = Pc[iy1[dy] * 8 + ix1[dx]];
                float pt = p00 + (p01 - p00) * fx[dx];
                float pb = p10 + (p11 - p10) * fx[dx];
                float p  = pt + (pb - pt) * fy[dy];
                a += DW[c * 9 + dy * 3 + dx] * p;
            }
        }
        g[c] = gelu_f(a);
    }
#pragma unroll
    for (int co = 0; co < 32; ++co) {
        float a = pwb[co];
#pragma unroll
        for (int c = 0; c < 32; ++c) a += PW[co * 32 + c] * g[c];
        att[co * 65536 + idx] = a;
    }
}

// ------------------------------------------------------------ att_zx/zy ----
__global__ void attz_kernel(const float* __restrict__ params_zx, const float* __restrict__ zx_dww,
                            const float* __restrict__ zx_dwb, const float* __restrict__ zx_pww,
                            const float* __restrict__ zx_pwb,
                            const float* __restrict__ params_zy, const float* __restrict__ zy_dww,
                            const float* __restrict__ zy_dwb, const float* __restrict__ zy_pww,
                            const float* __restrict__ zy_pwb,
                            float* __restrict__ att_zx, float* __restrict__ att_zy)
{
    const bool sel = (blockIdx.x != 0);
    const float* params = sel ? params_zy : params_zx;
    const float* dww = sel ? zy_dww : zx_dww;
    const float* dwb = sel ? zy_dwb : zx_dwb;
    const float* pww = sel ? zy_pww : zx_pww;
    const float* pwb = sel ? zy_pwb : zx_pwb;
    float* att = sel ? att_zy : att_zx;
    const int pos = threadIdx.x;
    float g[32];
#pragma unroll
    for (int c = 0; c < 32; ++c) {
        float a = dwb[c];
#pragma unroll
        for (int d = 0; d < 3; ++d) {
            int p = pos - 1 + d;
            if (p < 0 || p > 255) continue;
            float cz = p * (7.0f / 255.0f);
            int i0 = (int)floorf(cz); i0 = min(max(i0, 0), 7);
            int i1 = min(i0 + 1, 7);
            float f = cz - (float)i0;
            float pv = params[c * 8 + i0];
            pv += (params[c * 8 + i1] - pv) * f;
            a += dww[c * 3 + d] * pv;
        }
        g[c] = gelu_f(a);
    }
#pragma unroll
    for (int co = 0; co < 32; ++co) {
        float a = pwb[co];
#pragma unroll
        for (int ci = 0; ci < 32; ++ci) a += pww[co * 32 + ci] * g[ci];
        att[co * 256 + pos] = a;
    }
}

// -------------------------------------------- pw fp32 -> bf16 [co][ci] ----
__global__ void convert_pw_kernel(const float* __restrict__ pw, ushort_t* __restrict__ pwb16) {
    int i = blockIdx.x * 256 + threadIdx.x;
    pwb16[i] = f2bf(pw[i]);
}

// ------------------------------------------------------------- K1: ln1g ----
// thread = 1 pixel. LN1 stats over 128 ch -> stats map; x4 chunk -> pw+gelu -> g bf16
__global__ __launch_bounds__(256) void ln1g_kernel(
    const float* __restrict__ x,
    const float* __restrict__ n1w, const float* __restrict__ n1b,
    const float* __restrict__ pww, const float* __restrict__ pwb,
    ushort_t* __restrict__ g, float2* __restrict__ stats)
{
    const int b = blockIdx.x >> 8, h = blockIdx.x & 255, w = threadIdx.x;
    const float* xp = x + (((size_t)b * NC) * HH + h) * WW + w;
    float s1 = 0.f, s2 = 0.f;
    float x4v[32];
#pragma unroll
    for (int k = 0; k < 96; ++k) {
        float v = xp[(size_t)k * 65536];
        s1 += v; s2 += v * v;
    }
#pragma unroll
    for (int j = 0; j < 32; ++j) {
        float v = xp[(size_t)(96 + j) * 65536];
        x4v[j] = v; s1 += v; s2 += v * v;
    }
    float m = s1 * (1.f / 128.f);
    float r = rsqrtf(s2 * (1.f / 128.f) - m * m + 1e-6f);
    stats[(size_t)b * 65536 + h * WW + w] = float2{m, r};
#pragma unroll
    for (int j = 0; j < 32; ++j)
        x4v[j] = (x4v[j] - m) * r * n1w[96 + j] + n1b[96 + j];

    ushort_t* gp = g + (((size_t)b * 32) * HH + h) * WW + w;
#pragma unroll
    for (int co = 0; co < 32; ++co) {
        float a = pwb[co];
#pragma unroll
        for (int j = 0; j < 32; ++j) a += pww[co * 32 + j] * x4v[j];
        gp[(size_t)co * 65536] = f2bf(gelu_f(a));
    }
}

// ------------------------------------------------------------- K2: fuse ----
// Block = 64-px strip; 256 thr = 4 q-groups x 64 px. Thread handles 8 channels
// of EACH branch (balanced). x read once; LN1 from stats map; LN2 via LDS
// cross-q reduce; z bf16 out.
__global__ __launch_bounds__(256) void fuse_kernel(
    const float* __restrict__ x, const float2* __restrict__ stats,
    const float* __restrict__ n1w, const float* __restrict__ n1b,
    const float* __restrict__ n2w, const float* __restrict__ n2b,
    const float* __restrict__ att_xy, const float* __restrict__ att_zx,
    const float* __restrict__ att_zy,
    const ushort_t* __restrict__ g,
    const float* __restrict__ dww, const float* __restrict__ dwb,
    ushort_t* __restrict__ z)
{
    __shared__ float rs[4][64];
    __shared__ float rq[4][64];

    // XCD-chunked bijective swizzle (4096 % 8 == 0)
    const int lid  = (blockIdx.x & 7) * 512 + (blockIdx.x >> 3);
    const int b     = lid >> 10;
    const int h     = (lid >> 2) & 255;
    const int strip = lid & 3;
    const int q  = threadIdx.x >> 6;
    const int px = threadIdx.x & 63;
    const int w  = strip * 64 + px;
    const int pix = h * WW + w;

    const float2 st = stats[(size_t)b * 65536 + pix];
    const float m1 = st.x, r1 = st.y;

    float xn[4][8], u[4][8];
    // branches 0..2: att multiplies
#pragma unroll
    for (int br = 0; br < 3; ++br) {
#pragma unroll
        for (int j = 0; j < 8; ++j) {
            const int c = br * 32 + q * 8 + j;
            float xv = x[((size_t)(b * NC + c)) * 65536 + pix];
            float v = (xv - m1) * r1 * n1w[c] + n1b[c];
            xn[br][j] = v;
            float av;
            if (br == 0)      av = att_xy[(size_t)c * 65536 + pix];
            else if (br == 1) av = att_zx[(c - 32) * 256 + h];   // wave-uniform
            else              av = att_zy[(c - 64) * 256 + w];
            u[br][j] = v * av;
        }
    }
    // branch 3: dw3x3 over g
#pragma unroll
    for (int j = 0; j < 8; ++j) {
        const int k = q * 8 + j;
        const int c = 96 + k;
        float xv = x[((size_t)(b * NC + c)) * 65536 + pix];
        xn[3][j] = (xv - m1) * r1 * n1w[c] + n1b[c];
        float a = dwb[k];
        const ushort_t* gc = g + ((size_t)(b * 32 + k)) * 65536;
#pragma unroll
        for (int dy = -1; dy <= 1; ++dy) {
            int hy = h + dy;
            if (hy < 0 || hy > 255) continue;   // block-uniform
            const ushort_t* gr = gc + hy * WW + w;
            const float* wr = dww + k * 9 + (dy + 1) * 3;
            if (w > 0)   a += wr[0] * bf2f(gr[-1]);
                         a += wr[1] * bf2f(gr[0]);
            if (w < 255) a += wr[2] * bf2f(gr[1]);
        }
        u[3][j] = a;
    }
    // LN2 stats: partial over this thread's 32 channels, reduce across q
    float e1 = 0.f, e2 = 0.f;
#pragma unroll
    for (int br = 0; br < 4; ++br)
#pragma unroll
        for (int j = 0; j < 8; ++j) { e1 += u[br][j]; e2 += u[br][j] * u[br][j]; }
    rs[q][px] = e1; rq[q][px] = e2;
    __syncthreads();
    const float ssum = rs[0][px] + rs[1][px] + rs[2][px] + rs[3][px];
    const float qsum = rq[0][px] + rq[1][px] + rq[2][px] + rq[3][px];
    const float m2 = ssum * (1.f / 128.f);
    const float r2 = rsqrtf(qsum * (1.f / 128.f) - m2 * m2 + 1e-6f);
    // emit z = LN2(u) + xn
#pragma unroll
    for (int br = 0; br < 4; ++br) {
#pragma unroll
        for (int j = 0; j < 8; ++j) {
            const int c = br * 32 + q * 8 + j;
            z[((size_t)(b * NC + c)) * 65536 + pix] =
                f2bf((u[br][j] - m2) * r2 * n2w[c] + n2b[c] + xn[br][j]);
        }
    }
}

// --------------------------------------------------------------- ldw ----
// z (bf16) -> depthwise 3x3 -> gelu -> bf16 LDS tile -> MFMA 1x1 128->128 -> out
__global__ __launch_bounds__(256, 4) void ldw_kernel(
    const ushort_t* __restrict__ z, const float* __restrict__ dww,
    const float* __restrict__ dwb, const ushort_t* __restrict__ wb16,
    const float* __restrict__ pwb, float* __restrict__ out)
{
    __shared__ __align__(16) ushort_t tl[64 * 128];   // 16 KB

    const int lid  = (blockIdx.x & 7) * 512 + (blockIdx.x >> 3);
    const int b    = lid >> 10;
    const int h    = (lid >> 2) & 255;
    const int px0  = (lid & 3) * 64;

    const int tid  = threadIdx.x;
    const int lane = tid & 63;
    const int wv   = tid >> 6;
    const int l15  = lane & 15;
    const int l4   = lane >> 4;

    short8v afrag[2][4];
#pragma unroll
    for (int ct = 0; ct < 2; ++ct) {
        const int co = wv * 32 + ct * 16 + l15;
#pragma unroll
        for (int ks = 0; ks < 4; ++ks)
            afrag[ct][ks] = *(const short8v*)(wb16 + co * 128 + ks * 32 + l4 * 8);
    }
    float4v bias[2];
#pragma unroll
    for (int ct = 0; ct < 2; ++ct) {
        const float4 bv = *(const float4*)(pwb + wv * 32 + ct * 16 + l4 * 4);
        bias[ct] = float4v{bv.x, bv.y, bv.z, bv.w};
    }

    {
        const int px = lane;
        const int w  = px0 + px;
        const int cibase = wv * 32;
        char* tlb = (char*)tl;
#pragma unroll
        for (int k = 0; k < 32; k += 2) {
            float tv[2];
#pragma unroll
            for (int j = 0; j < 2; ++j) {
                const int c = cibase + k + j;
                const float* wk = dww + c * 9;
                float a = dwb[c];
                const ushort_t* zc = z + ((size_t)(b * NC + c)) * 65536;
#pragma unroll
                for (int dy = -1; dy <= 1; ++dy) {
                    int hy = h + dy;
                    if (hy < 0 || hy > 255) continue;
                    const ushort_t* zr = zc + hy * WW;
                    const float* wr = wk + (dy + 1) * 3;
                    if (w > 0)   a += wr[0] * bf2f(zr[w - 1]);
                                 a += wr[1] * bf2f(zr[w]);
                    if (w < 255) a += wr[2] * bf2f(zr[w + 1]);
                }
                tv[j] = gelu_f(a);
            }
            const int ci = cibase + k;
            const int chunk = (ci >> 3) ^ (px & 15);
            unsigned pack = (unsigned)f2bf(tv[0]) | ((unsigned)f2bf(tv[1]) << 16);
            *(unsigned*)(tlb + px * 256 + chunk * 16 + (ci & 7) * 2) = pack;
        }
    }
    __syncthreads();

    const char* tlb = (const char*)tl;
#pragma unroll
    for (int pt = 0; pt < 4; ++pt) {
        const int px = pt * 16 + l15;
        short8v bfrag[4];
#pragma unroll
        for (int ks = 0; ks < 4; ++ks) {
            const int chunk = (ks * 4 + l4) ^ (px & 15);
            bfrag[ks] = *(const short8v*)(tlb + px * 256 + chunk * 16);
        }
        float4v acc0 = bias[0];
        float4v acc1 = bias[1];
#pragma unroll
        for (int ks = 0; ks < 4; ++ks) {
            acc0 = __builtin_amdgcn_mfma_f32_16x16x32_bf16(afrag[0][ks], bfrag[ks], acc0, 0, 0, 0);
            acc1 = __builtin_amdgcn_mfma_f32_16x16x32_bf16(afrag[1][ks], bfrag[ks], acc1, 0, 0, 0);
        }
#pragma unroll
        for (int ct = 0; ct < 2; ++ct) {
            const int co = wv * 32 + ct * 16 + l4 * 4;
            float* op = out + ((size_t)(b * NC + co)) * 65536 + h * WW + px0 + pt * 16 + l15;
            const float4v av = ct ? acc1 : acc0;
#pragma unroll
            for (int r = 0; r < 4; ++r) op[(size_t)r * 65536] = av[r];
        }
    }
}

// ------------------------------------------------------------- launch ----
extern "C" void kernel_launch(void* const* d_in, const int* in_sizes, int n_in,
                              void* d_out, int out_size, void* d_ws, size_t ws_size,
                              hipStream_t stream)
{
    (void)in_sizes; (void)n_in; (void)out_size; (void)ws_size;
    const float* x       = (const float*)d_in[0];
    const float* n1w     = (const float*)d_in[1];
    const float* n1b     = (const float*)d_in[2];
    const float* pxy     = (const float*)d_in[3];
    const float* cxy_dww = (const float*)d_in[4];
    const float* cxy_dwb = (const float*)d_in[5];
    const float* cxy_pww = (const float*)d_in[6];
    const float* cxy_pwb = (const float*)d_in[7];
    const float* pzx     = (const float*)d_in[8];
    const float* czx_dww = (const float*)d_in[9];
    const float* czx_dwb = (const float*)d_in[10];
    const float* czx_pww = (const float*)d_in[11];
    const float* czx_pwb = (const float*)d_in[12];
    const float* pzy     = (const float*)d_in[13];
    const float* czy_dww = (const float*)d_in[14];
    const float* czy_dwb = (const float*)d_in[15];
    const float* czy_pww = (const float*)d_in[16];
    const float* czy_pwb = (const float*)d_in[17];
    const float* dw_pww  = (const float*)d_in[18];
    const float* dw_pwb  = (const float*)d_in[19];
    const float* dw_dww  = (const float*)d_in[20];
    const float* dw_dwb  = (const float*)d_in[21];
    const float* n2w     = (const float*)d_in[22];
    const float* n2b     = (const float*)d_in[23];
    const float* ldw_dww = (const float*)d_in[24];
    const float* ldw_dwb = (const float*)d_in[25];
    const float* ldw_pww = (const float*)d_in[26];
    const float* ldw_pwb = (const float*)d_in[27];
    float* out = (float*)d_out;
    char* ws   = (char*)d_ws;

    // ws: att_xy f32 8MB | att_zx 32KB | att_zy 32KB | pwb16 32KB |
    //     g u16 16MB | z u16 64MB | stats float2 2MB
    float* att_xy = (float*)ws;
    float* att_zx = att_xy + 32 * 65536;
    float* att_zy = att_zx + 32 * 256;
    ushort_t* pwb16 = (ushort_t*)(att_zy + 32 * 256);
    ushort_t* gbuf  = pwb16 + 128 * 128;
    ushort_t* zbuf  = gbuf + (size_t)4 * 32 * 65536;
    float2* stats   = (float2*)(zbuf + (size_t)4 * 128 * 65536);

    attxy_kernel<<<256, 256, 0, stream>>>(pxy, cxy_dww, cxy_dwb, cxy_pww, cxy_pwb, att_xy);
    attz_kernel<<<2, 256, 0, stream>>>(pzx, czx_dww, czx_dwb, czx_pww, czx_pwb,
                                       pzy, czy_dww, czy_dwb, czy_pww, czy_pwb,
                                       att_zx, att_zy);
    convert_pw_kernel<<<64, 256, 0, stream>>>(ldw_pww, pwb16);
    ln1g_kernel<<<1024, 256, 0, stream>>>(x, n1w, n1b, dw_pww, dw_pwb, gbuf, stats);
    fuse_kernel<<<4096, 256, 0, stream>>>(x, stats, n1w, n1b, n2w, n2b,
                                          att_xy, att_zx, att_zy,
                                          gbuf, dw_dww, dw_dwb, zbuf);
    ldw_kernel<<<4096, 256, 0, stream>>>(zbuf, ldw_dww, ldw_dwb, pwb16, ldw_pwb, out);
}

// Round 6
// 354.153 us; speedup vs baseline: 5.5747x; 1.2486x over previous
//
#include <hip/hip_runtime.h>
#include <hip/hip_bf16.h>
#include <math.h>

#define HH 256
#define WW 256
#define NB 4
#define NC 128
#define C4 32

typedef __attribute__((ext_vector_type(8))) short short8v;
typedef __attribute__((ext_vector_type(4))) float float4v;
typedef unsigned short ushort_t;

__device__ __forceinline__ float gelu_f(float v) {
    return 0.5f * v * (1.0f + erff(v * 0.7071067811865476f));
}
__device__ __forceinline__ unsigned short f2bf(float x) {
    __hip_bfloat16 h = __float2bfloat16(x);
    return __builtin_bit_cast(unsigned short, h);
}
__device__ __forceinline__ float bf2f(unsigned short u) {
    return __uint_as_float(((unsigned)u) << 16);
}
__device__ __forceinline__ float bfe(short8v v, int j) {
    return bf2f((ushort_t)v[j]);
}

// ------------------------------------------------- att_xy (NHWC out) ----
__global__ void attxy_kernel(const float* __restrict__ params,
                             const float* __restrict__ dww, const float* __restrict__ dwb,
                             const float* __restrict__ pww, const float* __restrict__ pwb,
                             float* __restrict__ att)   // att[pix][32]
{
    __shared__ float P[2048];
    __shared__ float DW[288];
    __shared__ float PW[1024];
    for (int i = threadIdx.x; i < 2048; i += 256) P[i] = params[i];
    for (int i = threadIdx.x; i < 288;  i += 256) DW[i] = dww[i];
    for (int i = threadIdx.x; i < 1024; i += 256) PW[i] = pww[i];
    __syncthreads();
    const int idx = blockIdx.x * 256 + threadIdx.x;
    const int h = idx >> 8, w = idx & 255;

    int iy0[3], iy1[3], ix0[3], ix1[3];
    float fy[3], fx[3];
    bool vy[3], vx[3];
#pragma unroll
    for (int d = 0; d < 3; ++d) {
        int hh = h - 1 + d;
        vy[d] = (hh >= 0 && hh < HH);
        float cy = hh * (7.0f / 255.0f);
        int i0 = (int)floorf(cy); i0 = min(max(i0, 0), 7);
        iy0[d] = i0; iy1[d] = min(i0 + 1, 7); fy[d] = cy - (float)i0;
        int ww2 = w - 1 + d;
        vx[d] = (ww2 >= 0 && ww2 < WW);
        float cx = ww2 * (7.0f / 255.0f);
        int j0 = (int)floorf(cx); j0 = min(max(j0, 0), 7);
        ix0[d] = j0; ix1[d] = min(j0 + 1, 7); fx[d] = cx - (float)j0;
    }
    float g[32];
#pragma unroll
    for (int c = 0; c < 32; ++c) {
        float a = dwb[c];
        const float* Pc = P + c * 64;
#pragma unroll
        for (int dy = 0; dy < 3; ++dy) {
            if (!vy[dy]) continue;
#pragma unroll
            for (int dx = 0; dx < 3; ++dx) {
                if (!vx[dx]) continue;
                float p00 = Pc[iy0[dy] * 8 + ix0[dx]];
                float p01 = Pc[iy0[dy] * 8 + ix1[dx]];
                float p10 = Pc[iy1[dy] * 8 + ix0[dx]];
                float p11 = Pc[iy1[dy] * 8 + ix1[dx]];
                float pt = p00 + (p01 - p00) * fx[dx];
                float pb = p10 + (p11 - p10) * fx[dx];
                float p  = pt + (pb - pt) * fy[dy];
                a += DW[c * 9 + dy * 3 + dx] * p;
            }
        }
        g[c] = gelu_f(a);
    }
    float o[32];
#pragma unroll
    for (int co = 0; co < 32; ++co) {
        float a = pwb[co];
#pragma unroll
        for (int c = 0; c < 32; ++c) a += PW[co * 32 + c] * g[c];
        o[co] = a;
    }
    float* ap = att + (size_t)idx * 32;
#pragma unroll
    for (int q = 0; q < 8; ++q)
        *(float4*)(ap + q * 4) = float4{o[q * 4], o[q * 4 + 1], o[q * 4 + 2], o[q * 4 + 3]};
}

// ------------------------------------------------------------ att_zx/zy ----
__global__ void attz_kernel(const float* __restrict__ params_zx, const float* __restrict__ zx_dww,
                            const float* __restrict__ zx_dwb, const float* __restrict__ zx_pww,
                            const float* __restrict__ zx_pwb,
                            const float* __restrict__ params_zy, const float* __restrict__ zy_dww,
                            const float* __restrict__ zy_dwb, const float* __restrict__ zy_pww,
                            const float* __restrict__ zy_pwb,
                            float* __restrict__ att_zx, float* __restrict__ att_zy)
{
    const bool sel = (blockIdx.x != 0);
    const float* params = sel ? params_zy : params_zx;
    const float* dww = sel ? zy_dww : zx_dww;
    const float* dwb = sel ? zy_dwb : zx_dwb;
    const float* pww = sel ? zy_pww : zx_pww;
    const float* pwb = sel ? zy_pwb : zx_pwb;
    float* att = sel ? att_zy : att_zx;
    const int pos = threadIdx.x;
    float g[32];
#pragma unroll
    for (int c = 0; c < 32; ++c) {
        float a = dwb[c];
#pragma unroll
        for (int d = 0; d < 3; ++d) {
            int p = pos - 1 + d;
            if (p < 0 || p > 255) continue;
            float cz = p * (7.0f / 255.0f);
            int i0 = (int)floorf(cz); i0 = min(max(i0, 0), 7);
            int i1 = min(i0 + 1, 7);
            float f = cz - (float)i0;
            float pv = params[c * 8 + i0];
            pv += (params[c * 8 + i1] - pv) * f;
            a += dww[c * 3 + d] * pv;
        }
        g[c] = gelu_f(a);
    }
#pragma unroll
    for (int co = 0; co < 32; ++co) {
        float a = pwb[co];
#pragma unroll
        for (int ci = 0; ci < 32; ++ci) a += pww[co * 32 + ci] * g[ci];
        att[co * 256 + pos] = a;
    }
}

// -------------------------------------------- pw fp32 -> bf16 [co][ci] ----
__global__ void convert_pw_kernel(const float* __restrict__ pw, ushort_t* __restrict__ pwb16) {
    int i = blockIdx.x * 256 + threadIdx.x;
    pwb16[i] = f2bf(pw[i]);
}

// ------------------------------------------------------------- K1: ln1g ----
// thread = 1 pixel. LN1 stats -> stats map; x4 chunk -> pw+gelu -> g NHWC bf16
__global__ __launch_bounds__(256) void ln1g_kernel(
    const float* __restrict__ x,
    const float* __restrict__ n1w, const float* __restrict__ n1b,
    const float* __restrict__ pww, const float* __restrict__ pwb,
    ushort_t* __restrict__ g, float2* __restrict__ stats)
{
    const int b = blockIdx.x >> 8, h = blockIdx.x & 255, w = threadIdx.x;
    const float* xp = x + (((size_t)b * NC) * HH + h) * WW + w;
    float s1 = 0.f, s2 = 0.f;
    float x4v[32];
#pragma unroll
    for (int k = 0; k < 96; ++k) {
        float v = xp[(size_t)k * 65536];
        s1 += v; s2 += v * v;
    }
#pragma unroll
    for (int j = 0; j < 32; ++j) {
        float v = xp[(size_t)(96 + j) * 65536];
        x4v[j] = v; s1 += v; s2 += v * v;
    }
    float m = s1 * (1.f / 128.f);
    float r = rsqrtf(s2 * (1.f / 128.f) - m * m + 1e-6f);
    stats[(size_t)b * 65536 + h * WW + w] = float2{m, r};
#pragma unroll
    for (int j = 0; j < 32; ++j)
        x4v[j] = (x4v[j] - m) * r * n1w[96 + j] + n1b[96 + j];

    float o[32];
#pragma unroll
    for (int co = 0; co < 32; ++co) {
        float a = pwb[co];
#pragma unroll
        for (int j = 0; j < 32; ++j) a += pww[co * 32 + j] * x4v[j];
        o[co] = gelu_f(a);
    }
    ushort_t* gp = g + ((size_t)b * 65536 + h * WW + w) * 32;
#pragma unroll
    for (int q = 0; q < 4; ++q) {
        short8v pk;
#pragma unroll
        for (int j = 0; j < 8; ++j) pk[j] = (short)f2bf(o[q * 8 + j]);
        *(short8v*)(gp + q * 8) = pk;
    }
}

// ------------------------------------------------------------- K2: fuse ----
// Block = 64-px strip; 256 thr = 4 q-groups x 64 px. NHWC g/att_xy/z.
__global__ __launch_bounds__(256) void fuse_kernel(
    const float* __restrict__ x, const float2* __restrict__ stats,
    const float* __restrict__ n1w, const float* __restrict__ n1b,
    const float* __restrict__ n2w, const float* __restrict__ n2b,
    const float* __restrict__ att_xy, const float* __restrict__ att_zx,
    const float* __restrict__ att_zy,
    const ushort_t* __restrict__ g,
    const float* __restrict__ dww, const float* __restrict__ dwb,
    ushort_t* __restrict__ z)
{
    __shared__ float rs[4][64];
    __shared__ float rq[4][64];

    const int lid  = (blockIdx.x & 7) * 512 + (blockIdx.x >> 3);
    const int b     = lid >> 10;
    const int h     = (lid >> 2) & 255;
    const int strip = lid & 3;
    const int q  = threadIdx.x >> 6;
    const int px = threadIdx.x & 63;
    const int w  = strip * 64 + px;
    const int pix = h * WW + w;

    const float2 st = stats[(size_t)b * 65536 + pix];
    const float m1 = st.x, r1 = st.y;

    float xn[4][8], u[4][8];
    // branch 0: att_xy (NHWC)
    {
        const float4 a0 = *(const float4*)(att_xy + (size_t)pix * 32 + q * 8);
        const float4 a1 = *(const float4*)(att_xy + (size_t)pix * 32 + q * 8 + 4);
        const float av[8] = {a0.x, a0.y, a0.z, a0.w, a1.x, a1.y, a1.z, a1.w};
#pragma unroll
        for (int j = 0; j < 8; ++j) {
            const int c = q * 8 + j;
            float xv = x[((size_t)(b * NC + c)) * 65536 + pix];
            float v = (xv - m1) * r1 * n1w[c] + n1b[c];
            xn[0][j] = v; u[0][j] = v * av[j];
        }
    }
#pragma unroll
    for (int j = 0; j < 8; ++j) {
        const int c = 32 + q * 8 + j;
        float xv = x[((size_t)(b * NC + c)) * 65536 + pix];
        float v = (xv - m1) * r1 * n1w[c] + n1b[c];
        xn[1][j] = v; u[1][j] = v * att_zx[(c - 32) * 256 + h];
    }
#pragma unroll
    for (int j = 0; j < 8; ++j) {
        const int c = 64 + q * 8 + j;
        float xv = x[((size_t)(b * NC + c)) * 65536 + pix];
        float v = (xv - m1) * r1 * n1w[c] + n1b[c];
        xn[2][j] = v; u[2][j] = v * att_zy[(c - 64) * 256 + w];
    }
    // branch 3: dw3x3 over NHWC g (8 channels per ushort8 tap)
    {
        float a[8];
#pragma unroll
        for (int j = 0; j < 8; ++j) a[j] = dwb[q * 8 + j];
        const int wl = (w > 0) ? w - 1 : 0;
        const int wr2 = (w < 255) ? w + 1 : 255;
        const float ml = (w > 0) ? 1.f : 0.f;
        const float mr = (w < 255) ? 1.f : 0.f;
#pragma unroll
        for (int dy = -1; dy <= 1; ++dy) {
            int hy = h + dy;
            if (hy < 0 || hy > 255) continue;   // block-uniform
            const ushort_t* gr = g + ((size_t)b * 65536 + hy * WW) * 32 + q * 8;
            short8v gl = *(const short8v*)(gr + (size_t)wl * 32);
            short8v gc = *(const short8v*)(gr + (size_t)w * 32);
            short8v gv = *(const short8v*)(gr + (size_t)wr2 * 32);
            const int r0 = (dy + 1) * 3;
#pragma unroll
            for (int j = 0; j < 8; ++j) {
                const float* wk = dww + (q * 8 + j) * 9 + r0;
                a[j] += (wk[0] * ml) * bfe(gl, j);
                a[j] += wk[1] * bfe(gc, j);
                a[j] += (wk[2] * mr) * bfe(gv, j);
            }
        }
#pragma unroll
        for (int j = 0; j < 8; ++j) {
            const int c = 96 + q * 8 + j;
            float xv = x[((size_t)(b * NC + c)) * 65536 + pix];
            xn[3][j] = (xv - m1) * r1 * n1w[c] + n1b[c];
            u[3][j] = a[j];
        }
    }
    // LN2 stats
    float e1 = 0.f, e2 = 0.f;
#pragma unroll
    for (int br = 0; br < 4; ++br)
#pragma unroll
        for (int j = 0; j < 8; ++j) { e1 += u[br][j]; e2 += u[br][j] * u[br][j]; }
    rs[q][px] = e1; rq[q][px] = e2;
    __syncthreads();
    const float ssum = rs[0][px] + rs[1][px] + rs[2][px] + rs[3][px];
    const float qsum = rq[0][px] + rq[1][px] + rq[2][px] + rq[3][px];
    const float m2 = ssum * (1.f / 128.f);
    const float r2 = rsqrtf(qsum * (1.f / 128.f) - m2 * m2 + 1e-6f);
    // emit z NHWC bf16
    ushort_t* zp = z + ((size_t)b * 65536 + pix) * 128;
#pragma unroll
    for (int br = 0; br < 4; ++br) {
        short8v pk;
#pragma unroll
        for (int j = 0; j < 8; ++j) {
            const int c = br * 32 + q * 8 + j;
            pk[j] = (short)f2bf((u[br][j] - m2) * r2 * n2w[c] + n2b[c] + xn[br][j]);
        }
        *(short8v*)(zp + br * 32 + q * 8) = pk;
    }
}

// --------------------------------------------------------------- ldw ----
// z NHWC bf16 -> dw3x3+gelu -> swizzled LDS -> MFMA 1x1 128->128 -> out NCHW f32
__global__ __launch_bounds__(256, 4) void ldw_kernel(
    const ushort_t* __restrict__ z, const float* __restrict__ dww,
    const float* __restrict__ dwb, const ushort_t* __restrict__ wb16,
    const float* __restrict__ pwb, float* __restrict__ out)
{
    __shared__ __align__(16) ushort_t tl[64 * 128];   // 16 KB  t[px][ci] swizzled

    const int lid  = (blockIdx.x & 7) * 512 + (blockIdx.x >> 3);
    const int b    = lid >> 10;
    const int h    = (lid >> 2) & 255;
    const int px0  = (lid & 3) * 64;

    const int tid  = threadIdx.x;
    const int lane = tid & 63;
    const int wv   = tid >> 6;
    const int l15  = lane & 15;
    const int l4   = lane >> 4;

    // ---- A fragments (W[co][ci] bf16) + bias ----
    short8v afrag[2][4];
#pragma unroll
    for (int ct = 0; ct < 2; ++ct) {
        const int co = wv * 32 + ct * 16 + l15;
#pragma unroll
        for (int ks = 0; ks < 4; ++ks)
            afrag[ct][ks] = *(const short8v*)(wb16 + co * 128 + ks * 32 + l4 * 8);
    }
    float4v bias[2];
#pragma unroll
    for (int ct = 0; ct < 2; ++ct) {
        const float4 bv = *(const float4*)(pwb + wv * 32 + ct * 16 + l4 * 4);
        bias[ct] = float4v{bv.x, bv.y, bv.z, bv.w};
    }

    // ---- phase 1: dw3x3 + gelu from NHWC z, 8-ch vector taps ----
    {
        const int px = lane;
        const int w  = px0 + px;
        const int wl = (w > 0) ? w - 1 : 0;
        const int wr2 = (w < 255) ? w + 1 : 255;
        const float ml = (w > 0) ? 1.f : 0.f;
        const float mr = (w < 255) ? 1.f : 0.f;
        char* tlb = (char*)tl;
#pragma unroll
        for (int batch = 0; batch < 4; ++batch) {
            const int cb = wv * 32 + batch * 8;
            float a[8];
#pragma unroll
            for (int j = 0; j < 8; ++j) a[j] = dwb[cb + j];
#pragma unroll
            for (int dy = -1; dy <= 1; ++dy) {
                int hy = h + dy;
                if (hy < 0 || hy > 255) continue;    // block-uniform
                const ushort_t* zr = z + ((size_t)b * 65536 + hy * WW) * 128 + cb;
                short8v vl = *(const short8v*)(zr + (size_t)wl * 128);
                short8v vc = *(const short8v*)(zr + (size_t)w * 128);
                short8v vr = *(const short8v*)(zr + (size_t)wr2 * 128);
                const int r0 = (dy + 1) * 3;
#pragma unroll
                for (int j = 0; j < 8; ++j) {
                    const float* wk = dww + (cb + j) * 9 + r0;
                    a[j] += (wk[0] * ml) * bfe(vl, j);
                    a[j] += wk[1] * bfe(vc, j);
                    a[j] += (wk[2] * mr) * bfe(vr, j);
                }
            }
            short8v pk;
#pragma unroll
            for (int j = 0; j < 8; ++j) pk[j] = (short)f2bf(gelu_f(a[j]));
            const int chunk = (cb >> 3) ^ (px & 15);
            *(short8v*)(tlb + px * 256 + chunk * 16) = pk;
        }
    }
    __syncthreads();

    // ---- phase 2: MFMA ----
    const char* tlb = (const char*)tl;
#pragma unroll
    for (int pt = 0; pt < 4; ++pt) {
        const int px = pt * 16 + l15;
        short8v bfrag[4];
#pragma unroll
        for (int ks = 0; ks < 4; ++ks) {
            const int chunk = (ks * 4 + l4) ^ (px & 15);
            bfrag[ks] = *(const short8v*)(tlb + px * 256 + chunk * 16);
        }
        float4v acc0 = bias[0];
        float4v acc1 = bias[1];
#pragma unroll
        for (int ks = 0; ks < 4; ++ks) {
            acc0 = __builtin_amdgcn_mfma_f32_16x16x32_bf16(afrag[0][ks], bfrag[ks], acc0, 0, 0, 0);
            acc1 = __builtin_amdgcn_mfma_f32_16x16x32_bf16(afrag[1][ks], bfrag[ks], acc1, 0, 0, 0);
        }
#pragma unroll
        for (int ct = 0; ct < 2; ++ct) {
            const int co = wv * 32 + ct * 16 + l4 * 4;
            float* op = out + ((size_t)(b * NC + co)) * 65536 + h * WW + px0 + pt * 16 + l15;
            const float4v av = ct ? acc1 : acc0;
#pragma unroll
            for (int r = 0; r < 4; ++r) op[(size_t)r * 65536] = av[r];
        }
    }
}

// ------------------------------------------------------------- launch ----
extern "C" void kernel_launch(void* const* d_in, const int* in_sizes, int n_in,
                              void* d_out, int out_size, void* d_ws, size_t ws_size,
                              hipStream_t stream)
{
    (void)in_sizes; (void)n_in; (void)out_size; (void)ws_size;
    const float* x       = (const float*)d_in[0];
    const float* n1w     = (const float*)d_in[1];
    const float* n1b     = (const float*)d_in[2];
    const float* pxy     = (const float*)d_in[3];
    const float* cxy_dww = (const float*)d_in[4];
    const float* cxy_dwb = (const float*)d_in[5];
    const float* cxy_pww = (const float*)d_in[6];
    const float* cxy_pwb = (const float*)d_in[7];
    const float* pzx     = (const float*)d_in[8];
    const float* czx_dww = (const float*)d_in[9];
    const float* czx_dwb = (const float*)d_in[10];
    const float* czx_pww = (const float*)d_in[11];
    const float* czx_pwb = (const float*)d_in[12];
    const float* pzy     = (const float*)d_in[13];
    const float* czy_dww = (const float*)d_in[14];
    const float* czy_dwb = (const float*)d_in[15];
    const float* czy_pww = (const float*)d_in[16];
    const float* czy_pwb = (const float*)d_in[17];
    const float* dw_pww  = (const float*)d_in[18];
    const float* dw_pwb  = (const float*)d_in[19];
    const float* dw_dww  = (const float*)d_in[20];
    const float* dw_dwb  = (const float*)d_in[21];
    const float* n2w     = (const float*)d_in[22];
    const float* n2b     = (const float*)d_in[23];
    const float* ldw_dww = (const float*)d_in[24];
    const float* ldw_dwb = (const float*)d_in[25];
    const float* ldw_pww = (const float*)d_in[26];
    const float* ldw_pwb = (const float*)d_in[27];
    float* out = (float*)d_out;
    char* ws   = (char*)d_ws;

    // ws: att_xy NHWC f32 8MB | att_zx 32KB | att_zy 32KB | pwb16 32KB |
    //     g NHWC u16 16MB | z NHWC u16 64MB | stats float2 2MB
    float* att_xy = (float*)ws;
    float* att_zx = att_xy + 32 * 65536;
    float* att_zy = att_zx + 32 * 256;
    ushort_t* pwb16 = (ushort_t*)(att_zy + 32 * 256);
    ushort_t* gbuf  = pwb16 + 128 * 128;
    ushort_t* zbuf  = gbuf + (size_t)4 * 32 * 65536;
    float2* stats   = (float2*)(zbuf + (size_t)4 * 128 * 65536);

    attxy_kernel<<<256, 256, 0, stream>>>(pxy, cxy_dww, cxy_dwb, cxy_pww, cxy_pwb, att_xy);
    attz_kernel<<<2, 256, 0, stream>>>(pzx, czx_dww, czx_dwb, czx_pww, czx_pwb,
                                       pzy, czy_dww, czy_dwb, czy_pww, czy_pwb,
                                       att_zx, att_zy);
    convert_pw_kernel<<<64, 256, 0, stream>>>(ldw_pww, pwb16);
    ln1g_kernel<<<1024, 256, 0, stream>>>(x, n1w, n1b, dw_pww, dw_pwb, gbuf, stats);
    fuse_kernel<<<4096, 256, 0, stream>>>(x, stats, n1w, n1b, n2w, n2b,
                                          att_xy, att_zx, att_zy,
                                          gbuf, dw_dww, dw_dwb, zbuf);
    ldw_kernel<<<4096, 256, 0, stream>>>(zbuf, ldw_dww, ldw_dwb, pwb16, ldw_pwb, out);
}

// Round 7
// 311.133 us; speedup vs baseline: 6.3455x; 1.1383x over previous
//
#include <hip/hip_runtime.h>
#include <hip/hip_bf16.h>
#include <math.h>

#define HH 256
#define WW 256
#define NB 4
#define NC 128
#define C4 32

typedef __attribute__((ext_vector_type(8))) short short8v;
typedef __attribute__((ext_vector_type(4))) float float4v;
typedef unsigned short ushort_t;

__device__ __forceinline__ float gelu_f(float v) {
    return 0.5f * v * (1.0f + erff(v * 0.7071067811865476f));
}
__device__ __forceinline__ unsigned short f2bf(float x) {
    __hip_bfloat16 h = __float2bfloat16(x);
    return __builtin_bit_cast(unsigned short, h);
}
__device__ __forceinline__ float bf2f(unsigned short u) {
    return __uint_as_float(((unsigned)u) << 16);
}
__device__ __forceinline__ float bfe(short8v v, int j) {
    return bf2f((ushort_t)v[j]);
}

// ------------------------------------------------- att_xy (NHWC out) ----
__global__ void attxy_kernel(const float* __restrict__ params,
                             const float* __restrict__ dww, const float* __restrict__ dwb,
                             const float* __restrict__ pww, const float* __restrict__ pwb,
                             float* __restrict__ att)   // att[pix][32]
{
    __shared__ float P[2048];
    __shared__ float DW[288];
    __shared__ float PW[1024];
    for (int i = threadIdx.x; i < 2048; i += 256) P[i] = params[i];
    for (int i = threadIdx.x; i < 288;  i += 256) DW[i] = dww[i];
    for (int i = threadIdx.x; i < 1024; i += 256) PW[i] = pww[i];
    __syncthreads();
    const int idx = blockIdx.x * 256 + threadIdx.x;
    const int h = idx >> 8, w = idx & 255;

    int iy0[3], iy1[3], ix0[3], ix1[3];
    float fy[3], fx[3];
    bool vy[3], vx[3];
#pragma unroll
    for (int d = 0; d < 3; ++d) {
        int hh = h - 1 + d;
        vy[d] = (hh >= 0 && hh < HH);
        float cy = hh * (7.0f / 255.0f);
        int i0 = (int)floorf(cy); i0 = min(max(i0, 0), 7);
        iy0[d] = i0; iy1[d] = min(i0 + 1, 7); fy[d] = cy - (float)i0;
        int ww2 = w - 1 + d;
        vx[d] = (ww2 >= 0 && ww2 < WW);
        float cx = ww2 * (7.0f / 255.0f);
        int j0 = (int)floorf(cx); j0 = min(max(j0, 0), 7);
        ix0[d] = j0; ix1[d] = min(j0 + 1, 7); fx[d] = cx - (float)j0;
    }
    float g[32];
#pragma unroll
    for (int c = 0; c < 32; ++c) {
        float a = dwb[c];
        const float* Pc = P + c * 64;
#pragma unroll
        for (int dy = 0; dy < 3; ++dy) {
            if (!vy[dy]) continue;
#pragma unroll
            for (int dx = 0; dx < 3; ++dx) {
                if (!vx[dx]) continue;
                float p00 = Pc[iy0[dy] * 8 + ix0[dx]];
                float p01 = Pc[iy0[dy] * 8 + ix1[dx]];
                float p10 = Pc[iy1[dy] * 8 + ix0[dx]];
                float p11 = Pc[iy1[dy] * 8 + ix1[dx]];
                float pt = p00 + (p01 - p00) * fx[dx];
                float pb = p10 + (p11 - p10) * fx[dx];
                float p  = pt + (pb - pt) * fy[dy];
                a += DW[c * 9 + dy * 3 + dx] * p;
            }
        }
        g[c] = gelu_f(a);
    }
    float o[32];
#pragma unroll
    for (int co = 0; co < 32; ++co) {
        float a = pwb[co];
#pragma unroll
        for (int c = 0; c < 32; ++c) a += PW[co * 32 + c] * g[c];
        o[co] = a;
    }
    float* ap = att + (size_t)idx * 32;
#pragma unroll
    for (int q = 0; q < 8; ++q)
        *(float4*)(ap + q * 4) = float4{o[q * 4], o[q * 4 + 1], o[q * 4 + 2], o[q * 4 + 3]};
}

// ------------------------------------------------------------ att_zx/zy ----
__global__ void attz_kernel(const float* __restrict__ params_zx, const float* __restrict__ zx_dww,
                            const float* __restrict__ zx_dwb, const float* __restrict__ zx_pww,
                            const float* __restrict__ zx_pwb,
                            const float* __restrict__ params_zy, const float* __restrict__ zy_dww,
                            const float* __restrict__ zy_dwb, const float* __restrict__ zy_pww,
                            const float* __restrict__ zy_pwb,
                            float* __restrict__ att_zx, float* __restrict__ att_zy)
{
    const bool sel = (blockIdx.x != 0);
    const float* params = sel ? params_zy : params_zx;
    const float* dww = sel ? zy_dww : zx_dww;
    const float* dwb = sel ? zy_dwb : zx_dwb;
    const float* pww = sel ? zy_pww : zx_pww;
    const float* pwb = sel ? zy_pwb : zx_pwb;
    float* att = sel ? att_zy : att_zx;
    const int pos = threadIdx.x;
    float g[32];
#pragma unroll
    for (int c = 0; c < 32; ++c) {
        float a = dwb[c];
#pragma unroll
        for (int d = 0; d < 3; ++d) {
            int p = pos - 1 + d;
            if (p < 0 || p > 255) continue;
            float cz = p * (7.0f / 255.0f);
            int i0 = (int)floorf(cz); i0 = min(max(i0, 0), 7);
            int i1 = min(i0 + 1, 7);
            float f = cz - (float)i0;
            float pv = params[c * 8 + i0];
            pv += (params[c * 8 + i1] - pv) * f;
            a += dww[c * 3 + d] * pv;
        }
        g[c] = gelu_f(a);
    }
#pragma unroll
    for (int co = 0; co < 32; ++co) {
        float a = pwb[co];
#pragma unroll
        for (int ci = 0; ci < 32; ++ci) a += pww[co * 32 + ci] * g[ci];
        att[co * 256 + pos] = a;
    }
}

// -------------------------------------------- pw fp32 -> bf16 [co][ci] ----
__global__ void convert_pw_kernel(const float* __restrict__ pw, ushort_t* __restrict__ pwb16) {
    int i = blockIdx.x * 256 + threadIdx.x;
    pwb16[i] = f2bf(pw[i]);
}

// ---------------------------------- ldw dw weights -> bf16 [tap][128] ----
__global__ void convert_ldwdw_kernel(const float* __restrict__ dww, ushort_t* __restrict__ dwwT) {
    int i = blockIdx.x * 256 + threadIdx.x;
    if (i < 1152) {
        int c = i / 9, tap = i % 9;
        dwwT[tap * 128 + c] = f2bf(dww[i]);
    }
}

// ------------------------------------------------------------- K1: ln1g ----
// thread = 1 pixel. LN1 stats -> stats map; x4 chunk -> pw+gelu -> g NHWC bf16
__global__ __launch_bounds__(256) void ln1g_kernel(
    const float* __restrict__ x,
    const float* __restrict__ n1w, const float* __restrict__ n1b,
    const float* __restrict__ pww, const float* __restrict__ pwb,
    ushort_t* __restrict__ g, float2* __restrict__ stats)
{
    const int b = blockIdx.x >> 8, h = blockIdx.x & 255, w = threadIdx.x;
    const float* xp = x + (((size_t)b * NC) * HH + h) * WW + w;
    float s1 = 0.f, s2 = 0.f;
    float x4v[32];
#pragma unroll
    for (int k = 0; k < 96; ++k) {
        float v = xp[(size_t)k * 65536];
        s1 += v; s2 += v * v;
    }
#pragma unroll
    for (int j = 0; j < 32; ++j) {
        float v = xp[(size_t)(96 + j) * 65536];
        x4v[j] = v; s1 += v; s2 += v * v;
    }
    float m = s1 * (1.f / 128.f);
    float r = rsqrtf(s2 * (1.f / 128.f) - m * m + 1e-6f);
    stats[(size_t)b * 65536 + h * WW + w] = float2{m, r};
#pragma unroll
    for (int j = 0; j < 32; ++j)
        x4v[j] = (x4v[j] - m) * r * n1w[96 + j] + n1b[96 + j];

    float o[32];
#pragma unroll
    for (int co = 0; co < 32; ++co) {
        float a = pwb[co];
#pragma unroll
        for (int j = 0; j < 32; ++j) a += pww[co * 32 + j] * x4v[j];
        o[co] = gelu_f(a);
    }
    ushort_t* gp = g + ((size_t)b * 65536 + h * WW + w) * 32;
#pragma unroll
    for (int q = 0; q < 4; ++q) {
        short8v pk;
#pragma unroll
        for (int j = 0; j < 8; ++j) pk[j] = (short)f2bf(o[q * 8 + j]);
        *(short8v*)(gp + q * 8) = pk;
    }
}

// ------------------------------------------------------------- K2: fuse ----
// Block = 64-px strip; 256 thr = 4 q-groups x 64 px. NHWC g/att_xy/z.
__global__ __launch_bounds__(256) void fuse_kernel(
    const float* __restrict__ x, const float2* __restrict__ stats,
    const float* __restrict__ n1w, const float* __restrict__ n1b,
    const float* __restrict__ n2w, const float* __restrict__ n2b,
    const float* __restrict__ att_xy, const float* __restrict__ att_zx,
    const float* __restrict__ att_zy,
    const ushort_t* __restrict__ g,
    const float* __restrict__ dww, const float* __restrict__ dwb,
    ushort_t* __restrict__ z)
{
    __shared__ float rs[4][64];
    __shared__ float rq[4][64];

    const int lid  = (blockIdx.x & 7) * 512 + (blockIdx.x >> 3);
    const int b     = lid >> 10;
    const int h     = (lid >> 2) & 255;
    const int strip = lid & 3;
    const int q  = threadIdx.x >> 6;
    const int px = threadIdx.x & 63;
    const int w  = strip * 64 + px;
    const int pix = h * WW + w;

    const float2 st = stats[(size_t)b * 65536 + pix];
    const float m1 = st.x, r1 = st.y;

    float xn[4][8], u[4][8];
    // branch 0: att_xy (NHWC)
    {
        const float4 a0 = *(const float4*)(att_xy + (size_t)pix * 32 + q * 8);
        const float4 a1 = *(const float4*)(att_xy + (size_t)pix * 32 + q * 8 + 4);
        const float av[8] = {a0.x, a0.y, a0.z, a0.w, a1.x, a1.y, a1.z, a1.w};
#pragma unroll
        for (int j = 0; j < 8; ++j) {
            const int c = q * 8 + j;
            float xv = x[((size_t)(b * NC + c)) * 65536 + pix];
            float v = (xv - m1) * r1 * n1w[c] + n1b[c];
            xn[0][j] = v; u[0][j] = v * av[j];
        }
    }
#pragma unroll
    for (int j = 0; j < 8; ++j) {
        const int c = 32 + q * 8 + j;
        float xv = x[((size_t)(b * NC + c)) * 65536 + pix];
        float v = (xv - m1) * r1 * n1w[c] + n1b[c];
        xn[1][j] = v; u[1][j] = v * att_zx[(c - 32) * 256 + h];
    }
#pragma unroll
    for (int j = 0; j < 8; ++j) {
        const int c = 64 + q * 8 + j;
        float xv = x[((size_t)(b * NC + c)) * 65536 + pix];
        float v = (xv - m1) * r1 * n1w[c] + n1b[c];
        xn[2][j] = v; u[2][j] = v * att_zy[(c - 64) * 256 + w];
    }
    // branch 3: dw3x3 over NHWC g (8 channels per ushort8 tap)
    {
        float a[8];
#pragma unroll
        for (int j = 0; j < 8; ++j) a[j] = dwb[q * 8 + j];
        const int wl = (w > 0) ? w - 1 : 0;
        const int wr2 = (w < 255) ? w + 1 : 255;
        const float ml = (w > 0) ? 1.f : 0.f;
        const float mr = (w < 255) ? 1.f : 0.f;
#pragma unroll
        for (int dy = -1; dy <= 1; ++dy) {
            int hy = h + dy;
            if (hy < 0 || hy > 255) continue;   // block-uniform
            const ushort_t* gr = g + ((size_t)b * 65536 + hy * WW) * 32 + q * 8;
            short8v gl = *(const short8v*)(gr + (size_t)wl * 32);
            short8v gc = *(const short8v*)(gr + (size_t)w * 32);
            short8v gv = *(const short8v*)(gr + (size_t)wr2 * 32);
            const int r0 = (dy + 1) * 3;
#pragma unroll
            for (int j = 0; j < 8; ++j) {
                const float* wk = dww + (q * 8 + j) * 9 + r0;
                a[j] += (wk[0] * ml) * bfe(gl, j);
                a[j] += wk[1] * bfe(gc, j);
                a[j] += (wk[2] * mr) * bfe(gv, j);
            }
        }
#pragma unroll
        for (int j = 0; j < 8; ++j) {
            const int c = 96 + q * 8 + j;
            float xv = x[((size_t)(b * NC + c)) * 65536 + pix];
            xn[3][j] = (xv - m1) * r1 * n1w[c] + n1b[c];
            u[3][j] = a[j];
        }
    }
    // LN2 stats
    float e1 = 0.f, e2 = 0.f;
#pragma unroll
    for (int br = 0; br < 4; ++br)
#pragma unroll
        for (int j = 0; j < 8; ++j) { e1 += u[br][j]; e2 += u[br][j] * u[br][j]; }
    rs[q][px] = e1; rq[q][px] = e2;
    __syncthreads();
    const float ssum = rs[0][px] + rs[1][px] + rs[2][px] + rs[3][px];
    const float qsum = rq[0][px] + rq[1][px] + rq[2][px] + rq[3][px];
    const float m2 = ssum * (1.f / 128.f);
    const float r2 = rsqrtf(qsum * (1.f / 128.f) - m2 * m2 + 1e-6f);
    // emit z NHWC bf16
    ushort_t* zp = z + ((size_t)b * 65536 + pix) * 128;
#pragma unroll
    for (int br = 0; br < 4; ++br) {
        short8v pk;
#pragma unroll
        for (int j = 0; j < 8; ++j) {
            const int c = br * 32 + q * 8 + j;
            pk[j] = (short)f2bf((u[br][j] - m2) * r2 * n2w[c] + n2b[c] + xn[br][j]);
        }
        *(short8v*)(zp + br * 32 + q * 8) = pk;
    }
}

// --------------------------------------------------------------- ldw ----
// z NHWC bf16 -> dw3x3+gelu (channel-major lanes) -> swizzled LDS -> MFMA -> out
__global__ __launch_bounds__(256, 3) void ldw_kernel(
    const ushort_t* __restrict__ z, const ushort_t* __restrict__ dwwT,
    const float* __restrict__ dwb, const ushort_t* __restrict__ wb16,
    const float* __restrict__ pwb, float* __restrict__ out)
{
    __shared__ __align__(16) ushort_t tl[64 * 128];   // 16 KB  t[px][ci] swizzled

    const int lid  = (blockIdx.x & 7) * 512 + (blockIdx.x >> 3);
    const int b    = lid >> 10;
    const int h    = (lid >> 2) & 255;
    const int px0  = (lid & 3) * 64;

    const int tid  = threadIdx.x;
    const int lane = tid & 63;
    const int wv   = tid >> 6;
    const int l15  = lane & 15;
    const int l4   = lane >> 4;

    // ---- A fragments (W[co][ci] bf16) + bias ----
    short8v afrag[2][4];
#pragma unroll
    for (int ct = 0; ct < 2; ++ct) {
        const int co = wv * 32 + ct * 16 + l15;
#pragma unroll
        for (int ks = 0; ks < 4; ++ks)
            afrag[ct][ks] = *(const short8v*)(wb16 + co * 128 + ks * 32 + l4 * 8);
    }
    float4v bias[2];
#pragma unroll
    for (int ct = 0; ct < 2; ++ct) {
        const float4 bv = *(const float4*)(pwb + wv * 32 + ct * 16 + l4 * 4);
        bias[ct] = float4v{bv.x, bv.y, bv.z, bv.w};
    }

    // ---- phase 1: dw3x3 + gelu, channel-major lanes (oc = tid&15) ----
    {
        const int oc = tid & 15;          // channel octet: ci = oc*8..oc*8+7
        const int pr = tid >> 4;          // 0..15
        // hoisted weights: 9 taps x 8 ch (bf16) + 8 biases
        short8v wt[9];
#pragma unroll
        for (int t = 0; t < 9; ++t)
            wt[t] = *(const short8v*)(dwwT + t * 128 + oc * 8);
        const float4 bd0 = *(const float4*)(dwb + oc * 8);
        const float4 bd1 = *(const float4*)(dwb + oc * 8 + 4);
        const float bdw[8] = {bd0.x, bd0.y, bd0.z, bd0.w, bd1.x, bd1.y, bd1.z, bd1.w};
        char* tlb = (char*)tl;
#pragma unroll
        for (int it = 0; it < 4; ++it) {
            const int px = it * 16 + pr;
            const int w  = px0 + px;
            const int wl = (w > 0) ? w - 1 : 0;
            const int wr2 = (w < 255) ? w + 1 : 255;
            const float ml = (w > 0) ? 1.f : 0.f;
            const float mr = (w < 255) ? 1.f : 0.f;
            float a[8];
#pragma unroll
            for (int j = 0; j < 8; ++j) a[j] = bdw[j];
#pragma unroll
            for (int dy = -1; dy <= 1; ++dy) {
                int hy = h + dy;
                if (hy < 0 || hy > 255) continue;    // block-uniform
                const ushort_t* zr = z + ((size_t)b * 65536 + hy * WW) * 128 + oc * 8;
                short8v vl = *(const short8v*)(zr + (size_t)wl * 128);
                short8v vc = *(const short8v*)(zr + (size_t)w * 128);
                short8v vr = *(const short8v*)(zr + (size_t)wr2 * 128);
                const int r0 = (dy + 1) * 3;
#pragma unroll
                for (int j = 0; j < 8; ++j) {
                    a[j] += (bfe(wt[r0], j) * ml) * bfe(vl, j);
                    a[j] += bfe(wt[r0 + 1], j) * bfe(vc, j);
                    a[j] += (bfe(wt[r0 + 2], j) * mr) * bfe(vr, j);
                }
            }
            short8v pk;
#pragma unroll
            for (int j = 0; j < 8; ++j) pk[j] = (short)f2bf(gelu_f(a[j]));
            const int chunk = oc ^ (px & 15);
            *(short8v*)(tlb + px * 256 + chunk * 16) = pk;
        }
    }
    __syncthreads();

    // ---- phase 2: MFMA ----
    const char* tlb = (const char*)tl;
#pragma unroll
    for (int pt = 0; pt < 4; ++pt) {
        const int px = pt * 16 + l15;
        short8v bfrag[4];
#pragma unroll
        for (int ks = 0; ks < 4; ++ks) {
            const int chunk = (ks * 4 + l4) ^ (px & 15);
            bfrag[ks] = *(const short8v*)(tlb + px * 256 + chunk * 16);
        }
        float4v acc0 = bias[0];
        float4v acc1 = bias[1];
#pragma unroll
        for (int ks = 0; ks < 4; ++ks) {
            acc0 = __builtin_amdgcn_mfma_f32_16x16x32_bf16(afrag[0][ks], bfrag[ks], acc0, 0, 0, 0);
            acc1 = __builtin_amdgcn_mfma_f32_16x16x32_bf16(afrag[1][ks], bfrag[ks], acc1, 0, 0, 0);
        }
#pragma unroll
        for (int ct = 0; ct < 2; ++ct) {
            const int co = wv * 32 + ct * 16 + l4 * 4;
            float* op = out + ((size_t)(b * NC + co)) * 65536 + h * WW + px0 + pt * 16 + l15;
            const float4v av = ct ? acc1 : acc0;
#pragma unroll
            for (int r = 0; r < 4; ++r) op[(size_t)r * 65536] = av[r];
        }
    }
}

// ------------------------------------------------------------- launch ----
extern "C" void kernel_launch(void* const* d_in, const int* in_sizes, int n_in,
                              void* d_out, int out_size, void* d_ws, size_t ws_size,
                              hipStream_t stream)
{
    (void)in_sizes; (void)n_in; (void)out_size; (void)ws_size;
    const float* x       = (const float*)d_in[0];
    const float* n1w     = (const float*)d_in[1];
    const float* n1b     = (const float*)d_in[2];
    const float* pxy     = (const float*)d_in[3];
    const float* cxy_dww = (const float*)d_in[4];
    const float* cxy_dwb = (const float*)d_in[5];
    const float* cxy_pww = (const float*)d_in[6];
    const float* cxy_pwb = (const float*)d_in[7];
    const float* pzx     = (const float*)d_in[8];
    const float* czx_dww = (const float*)d_in[9];
    const float* czx_dwb = (const float*)d_in[10];
    const float* czx_pww = (const float*)d_in[11];
    const float* czx_pwb = (const float*)d_in[12];
    const float* pzy     = (const float*)d_in[13];
    const float* czy_dww = (const float*)d_in[14];
    const float* czy_dwb = (const float*)d_in[15];
    const float* czy_pww = (const float*)d_in[16];
    const float* czy_pwb = (const float*)d_in[17];
    const float* dw_pww  = (const float*)d_in[18];
    const float* dw_pwb  = (const float*)d_in[19];
    const float* dw_dww  = (const float*)d_in[20];
    const float* dw_dwb  = (const float*)d_in[21];
    const float* n2w     = (const float*)d_in[22];
    const float* n2b     = (const float*)d_in[23];
    const float* ldw_dww = (const float*)d_in[24];
    const float* ldw_dwb = (const float*)d_in[25];
    const float* ldw_pww = (const float*)d_in[26];
    const float* ldw_pwb = (const float*)d_in[27];
    float* out = (float*)d_out;
    char* ws   = (char*)d_ws;

    // ws: att_xy NHWC f32 8MB | att_zx 32KB | att_zy 32KB | pwb16 32KB |
    //     dwwT 4KB | g NHWC u16 16MB | z NHWC u16 64MB | stats float2 2MB
    float* att_xy = (float*)ws;
    float* att_zx = att_xy + 32 * 65536;
    float* att_zy = att_zx + 32 * 256;
    ushort_t* pwb16 = (ushort_t*)(att_zy + 32 * 256);
    ushort_t* dwwT  = pwb16 + 128 * 128;
    ushort_t* gbuf  = dwwT + 2048;
    ushort_t* zbuf  = gbuf + (size_t)4 * 32 * 65536;
    float2* stats   = (float2*)(zbuf + (size_t)4 * 128 * 65536);

    attxy_kernel<<<256, 256, 0, stream>>>(pxy, cxy_dww, cxy_dwb, cxy_pww, cxy_pwb, att_xy);
    attz_kernel<<<2, 256, 0, stream>>>(pzx, czx_dww, czx_dwb, czx_pww, czx_pwb,
                                       pzy, czy_dww, czy_dwb, czy_pww, czy_pwb,
                                       att_zx, att_zy);
    convert_pw_kernel<<<64, 256, 0, stream>>>(ldw_pww, pwb16);
    convert_ldwdw_kernel<<<5, 256, 0, stream>>>(ldw_dww, dwwT);
    ln1g_kernel<<<1024, 256, 0, stream>>>(x, n1w, n1b, dw_pww, dw_pwb, gbuf, stats);
    fuse_kernel<<<4096, 256, 0, stream>>>(x, stats, n1w, n1b, n2w, n2b,
                                          att_xy, att_zx, att_zy,
                                          gbuf, dw_dww, dw_dwb, zbuf);
    ldw_kernel<<<4096, 256, 0, stream>>>(zbuf, dwwT, ldw_dwb, pwb16, ldw_pwb, out);
}